// Round 9
// baseline (159.936 us; speedup 1.0000x reference)
//
#include <hip/hip_runtime.h>

// Problem constants
#define BB 2
#define SQ 2048
#define SK 2048
#define DD 1024
#define HH 16
#define HS 64
#define SCALE 0.125f
#define LOG2E 1.4426950408889634f

typedef __bf16 bf16x8 __attribute__((ext_vector_type(8)));
typedef float f32x4 __attribute__((ext_vector_type(4)));
typedef unsigned int uint;

__device__ __forceinline__ void gload_lds16(const __bf16* g, __bf16* l) {
    __builtin_amdgcn_global_load_lds((const __attribute__((address_space(1))) uint*)(g),
                                     (__attribute__((address_space(3))) uint*)(l), 16, 0, 0);
}

// ---------------- cast fp32 -> bf16 (both inputs in one launch) ----------------
__global__ void cast2_f32_bf16(const float* __restrict__ in0, const float* __restrict__ in1,
                               __bf16* __restrict__ out0, __bf16* __restrict__ out1, int n8each) {
    int i = blockIdx.x * blockDim.x + threadIdx.x;
    const float* src;
    __bf16* dst;
    int j;
    if (i < n8each) { src = in0; dst = out0; j = i; }
    else            { src = in1; dst = out1; j = i - n8each; }
    const float4* p = ((const float4*)src) + (size_t)j * 2;
    float4 a = p[0], b = p[1];
    bf16x8 v = {(__bf16)a.x, (__bf16)a.y, (__bf16)a.z, (__bf16)a.w,
                (__bf16)b.x, (__bf16)b.y, (__bf16)b.z, (__bf16)b.w};
    ((bf16x8*)dst)[j] = v;
}

// ------------- cast+transpose the 4 weight matrices [K][N] -> bf16 [N][K] -------------
__global__ void wtrans(const float* __restrict__ W0, const float* __restrict__ W1,
                       const float* __restrict__ W2, const float* __restrict__ W3,
                       __bf16* __restrict__ Wt) {
    __shared__ __bf16 tile[32][33];
    const float* W = blockIdx.z == 0 ? W0 : blockIdx.z == 1 ? W1 : blockIdx.z == 2 ? W2 : W3;
    __bf16* out = Wt + (size_t)blockIdx.z * DD * DD;
    int tx = threadIdx.x, ty = threadIdx.y;     // (32, 8)
    int k0 = blockIdx.y * 32, n0 = blockIdx.x * 32;
#pragma unroll
    for (int j = 0; j < 4; ++j)
        tile[ty + j * 8][tx] = (__bf16)W[(size_t)(k0 + ty + j * 8) * DD + n0 + tx];
    __syncthreads();
#pragma unroll
    for (int j = 0; j < 4; ++j)
        out[(size_t)(n0 + ty + j * 8) * DD + k0 + tx] = tile[tx][ty + j * 8];
}

// ------------- GEMM body: acc = A[4096,1024] @ Bt[1024,1024]^T -------------
// 128x128 tile, BK=64, 256 threads (4 waves, 64x64 quadrant each), global_load_lds staging
// MODE 0: C = bf16 (acc+bias)*scale ; MODE 2: transposed + kv-bit-permuted Vt write
#define BM 128
#define BN 128
#define BK 64
template <int MODE>
__device__ __forceinline__ void gemm_body(const __bf16* __restrict__ A, const __bf16* __restrict__ Bt,
                                          const float* __restrict__ bias, void* __restrict__ Cout,
                                          float scale) {
    __shared__ __bf16 As[BM][BK];
    __shared__ __bf16 Bs[BN][BK];
    int t = threadIdx.x;
    int w = t >> 6, l = t & 63;
    int lm = l & 15, lk = l >> 4;
    int wr = w >> 1, wc = w & 1;
    int br = blockIdx.y, bc = blockIdx.x;
    int srow = (l >> 3), scol = (l & 7) * 8;
    f32x4 acc[4][4] = {};
    for (int kt = 0; kt < 1024; kt += BK) {
        __syncthreads();
#pragma unroll
        for (int j = 0; j < 4; ++j) {
            int r0 = (w * 4 + j) * 8;
            gload_lds16(&A[(size_t)(br * BM + r0 + srow) * 1024 + kt + scol], &As[r0][0]);
            gload_lds16(&Bt[(size_t)(bc * BN + r0 + srow) * 1024 + kt + scol], &Bs[r0][0]);
        }
        __syncthreads();
#pragma unroll
        for (int kk = 0; kk < BK; kk += 32) {
            bf16x8 af[4], bf[4];
#pragma unroll
            for (int m = 0; m < 4; ++m) af[m] = *(const bf16x8*)&As[wr * 64 + m * 16 + lm][kk + lk * 8];
#pragma unroll
            for (int n = 0; n < 4; ++n) bf[n] = *(const bf16x8*)&Bs[wc * 64 + n * 16 + lm][kk + lk * 8];
#pragma unroll
            for (int m = 0; m < 4; ++m)
#pragma unroll
                for (int n = 0; n < 4; ++n)
                    acc[m][n] = __builtin_amdgcn_mfma_f32_16x16x32_bf16(af[m], bf[n], acc[m][n], 0, 0, 0);
        }
    }
#pragma unroll
    for (int m = 0; m < 4; ++m)
#pragma unroll
        for (int n = 0; n < 4; ++n) {
            int col = bc * BN + wc * 64 + n * 16 + lm;
            float bv = bias[col];
            if constexpr (MODE == 2) {
                // Vt value for key-pos sk stored at sigma-permuted position:
                // within 64-block: p = o5<<5 | o3<<4 | o2<<3 | o4<<2 | o1o0  (o = sk & 63)
                int row = br * BM + wr * 64 + m * 16 + lk * 4;   // sk0 (multiple of 4)
                int b_ = row >> 11, sk = row & 2047;
                int skb = sk & ~63, o = sk & 63;
                int p0 = (o & 32) | (((o >> 3) & 1) << 4) | (((o >> 2) & 1) << 3) | (((o >> 4) & 1) << 2);
                int h_ = col >> 6, d_ = col & 63;
                union { ushort4 u; __bf16 h[4]; } pk;
#pragma unroll
                for (int r = 0; r < 4; ++r) pk.h[r] = (__bf16)(acc[m][n][r] + bv);
                *(ushort4*)((__bf16*)Cout + ((size_t)((b_ * 16 + h_) * 64 + d_) * 2048 + skb + p0)) = pk.u;
            } else {
#pragma unroll
                for (int r = 0; r < 4; ++r) {
                    int row = br * BM + wr * 64 + m * 16 + lk * 4 + r;
                    ((__bf16*)Cout)[(size_t)row * 1024 + col] = (__bf16)((acc[m][n][r] + bv) * scale);
                }
            }
        }
}

// fused Q/K/V projections: z==0 -> Q (scaled), z==1 -> K, z==2 -> V written transposed+permuted as Vt
__global__ __launch_bounds__(256) void gemm_qkv(const __bf16* __restrict__ Ain, const __bf16* __restrict__ Actx,
                                                const __bf16* __restrict__ Wt,
                                                const float* __restrict__ bq, const float* __restrict__ bk,
                                                const float* __restrict__ bv,
                                                __bf16* __restrict__ Qb, __bf16* __restrict__ Kb,
                                                __bf16* __restrict__ Vtb, float qscale) {
    int z = blockIdx.z;
    const __bf16* A = (z == 0) ? Ain : Actx;
    const __bf16* B = Wt + (size_t)z * DD * DD;
    if (z == 0)      gemm_body<0>(A, B, bq, Qb, qscale);
    else if (z == 1) gemm_body<0>(A, B, bk, Kb, 1.f);
    else             gemm_body<2>(A, B, bv, Vtb, 1.f);
}

// ------------- output GEMM: 64x128 tile (grid 512 = 2 blocks/CU), float out -------------
__global__ __launch_bounds__(256) void gemm_out64(const __bf16* __restrict__ A, const __bf16* __restrict__ Bt,
                                                  const float* __restrict__ bias, float* __restrict__ C) {
    __shared__ __bf16 As[64][64];
    __shared__ __bf16 Bs[128][64];
    int t = threadIdx.x;
    int w = t >> 6, l = t & 63;
    int lm = l & 15, lk = l >> 4;
    int br = blockIdx.y, bc = blockIdx.x;   // grid (8, 64)
    int srow = (l >> 3), scol = (l & 7) * 8;
    f32x4 acc[4][2] = {};
    for (int kt = 0; kt < 1024; kt += 64) {
        __syncthreads();
#pragma unroll
        for (int j = 0; j < 2; ++j) {
            int r0 = (j * 4 + w) * 8;
            gload_lds16(&A[(size_t)(br * 64 + r0 + srow) * 1024 + kt + scol], &As[r0][0]);
        }
#pragma unroll
        for (int j = 0; j < 4; ++j) {
            int r0 = (j * 4 + w) * 8;
            gload_lds16(&Bt[(size_t)(bc * 128 + r0 + srow) * 1024 + kt + scol], &Bs[r0][0]);
        }
        __syncthreads();
#pragma unroll
        for (int kk = 0; kk < 64; kk += 32) {
            bf16x8 af[4], bf[2];
#pragma unroll
            for (int m = 0; m < 4; ++m) af[m] = *(const bf16x8*)&As[m * 16 + lm][kk + lk * 8];
#pragma unroll
            for (int n = 0; n < 2; ++n) bf[n] = *(const bf16x8*)&Bs[w * 32 + n * 16 + lm][kk + lk * 8];
#pragma unroll
            for (int m = 0; m < 4; ++m)
#pragma unroll
                for (int n = 0; n < 2; ++n)
                    acc[m][n] = __builtin_amdgcn_mfma_f32_16x16x32_bf16(af[m], bf[n], acc[m][n], 0, 0, 0);
        }
    }
#pragma unroll
    for (int m = 0; m < 4; ++m)
#pragma unroll
        for (int n = 0; n < 2; ++n) {
            int col = bc * 128 + w * 32 + n * 16 + lm;
            float bv = bias[col];
#pragma unroll
            for (int r = 0; r < 4; ++r) {
                int row = br * 64 + m * 16 + lk * 4 + r;
                C[(size_t)row * 1024 + col] = acc[m][n][r] + bv;
            }
        }
}

// ------------- flash attention, swapped-QK^T (S^T), lane-local P -------------
// QBLK=128: 4 waves x 32 q-rows; KVBLK=64, double-buffered K/V, 1 barrier/tile.
// NZ=2: kv range split across blockIdx.z (partials are EXACTLY additive since softmax
// has no running max) -> 1024 blocks = 4 blocks/CU = 4 waves/SIMD, fills VALU issue.
// Partial o (fp32, unnormalized) + partial rowsums go to workspace; combine divides.
// NZ=1: fallback single-pass writing bf16 directly (if workspace too small).
template <int NZ>
__global__ __launch_bounds__(256, 4) void flash_attn(const __bf16* __restrict__ Q,
                                                     const __bf16* __restrict__ Kb,
                                                     const __bf16* __restrict__ Vt,
                                                     __bf16* __restrict__ O,
                                                     float* __restrict__ po,
                                                     float* __restrict__ ps) {
    __shared__ __bf16 Ks[2][64 * 64];
    __shared__ __bf16 Vs[2][64 * 64];
    int t = threadIdx.x, w = t >> 6, l = t & 63;
    int lm = l & 15, lk = l >> 4;
    int bh = blockIdx.y, b = bh >> 4, h = bh & 15;
    int q0 = blockIdx.x * 128;
    const int NT = 32 / NZ;
    const int kvbase = (NZ == 2) ? (int)blockIdx.z * (SK / NZ) : 0;

    // Q fragments straight from global (one-time): wave w owns q rows q0+w*32 .. +31
    bf16x8 qf[2][2];
#pragma unroll
    for (int m = 0; m < 2; ++m)
#pragma unroll
        for (int kk = 0; kk < 2; ++kk)
            qf[m][kk] = *(const bf16x8*)&Q[(size_t)(b * SQ + q0 + w * 32 + m * 16 + lm) * DD + h * HS + kk * 32 + lk * 8];

    // staging geometry: thread covers rows r0 and r0+32, 8-elem chunk c8; swizzled chunk c8^(r0&7)
    int r0 = t >> 3, c8 = t & 7;
    int chs = c8 ^ (r0 & 7);
    const __bf16* kbase = Kb + (size_t)b * SK * DD + h * HS;      // + (kv+row)*DD + c8*8
    const __bf16* vbase = Vt + (size_t)bh * HS * SK;              // + d*SK + kv + c8*8 (pre-permuted)
    __bf16* ksl0 = &Ks[0][(r0)      * 64 + chs * 8];
    __bf16* ksl1 = &Ks[0][(r0 + 32) * 64 + chs * 8];
    __bf16* vsl0 = &Vs[0][(r0)      * 64 + chs * 8];
    __bf16* vsl1 = &Vs[0][(r0 + 32) * 64 + chs * 8];

    float4 kr0, kr1, vr0, vr1;   // NAMED regs only (arrays -> scratch)
#define FA_LOAD(KV)                                                              \
    kr0 = *(const float4*)&kbase[(size_t)((KV) + r0) * DD + c8 * 8];             \
    kr1 = *(const float4*)&kbase[(size_t)((KV) + r0 + 32) * DD + c8 * 8];        \
    vr0 = *(const float4*)&vbase[(size_t)(r0) * SK + (KV) + c8 * 8];             \
    vr1 = *(const float4*)&vbase[(size_t)(r0 + 32) * SK + (KV) + c8 * 8];
#define FA_WRITE(BUF)                                                            \
    *(float4*)(ksl0 + (BUF) * 4096) = kr0;                                       \
    *(float4*)(ksl1 + (BUF) * 4096) = kr1;                                       \
    *(float4*)(vsl0 + (BUF) * 4096) = vr0;                                       \
    *(float4*)(vsl1 + (BUF) * 4096) = vr1;

    FA_LOAD(kvbase);
    FA_WRITE(0);
    __syncthreads();

    bf16x8 ones;
#pragma unroll
    for (int j = 0; j < 8; ++j) ones[j] = (__bf16)1.0f;

    f32x4 o[2][4] = {};
    f32x4 o_s[2] = {};

    for (int it = 0; it < NT; ++it) {
        int buf = it & 1;
        if (it + 1 < NT) { FA_LOAD(kvbase + (it + 1) * 64); }   // issue early; hides under compute

        const __bf16* KsB = &Ks[buf][0];
        const __bf16* VsB = &Vs[buf][0];

        // S^T = K Q^T : st[n][m], lane holds P[q=m*16+lm][kv=16n+4lk+r]
        f32x4 st[4][2] = {};
        __builtin_amdgcn_s_setprio(1);
#pragma unroll
        for (int kk = 0; kk < 2; ++kk) {
            bf16x8 kf[4];
#pragma unroll
            for (int n = 0; n < 4; ++n)
                kf[n] = *(const bf16x8*)&KsB[(n * 16 + lm) * 64 + (((kk * 4 + lk) ^ (lm & 7)) * 8)];
#pragma unroll
            for (int n = 0; n < 4; ++n)
#pragma unroll
                for (int m = 0; m < 2; ++m)
                    st[n][m] = __builtin_amdgcn_mfma_f32_16x16x32_bf16(kf[n], qf[m][kk], st[n][m], 0, 0, 0);
        }
        __builtin_amdgcn_s_setprio(0);

        // P = exp2(S) fused into fragment assembly; PV + ones-column row-sum
#pragma unroll
        for (int kk = 0; kk < 2; ++kk) {
            bf16x8 pa[2], vf[4];
#pragma unroll
            for (int m = 0; m < 2; ++m)
#pragma unroll
                for (int j = 0; j < 8; ++j)
                    pa[m][j] = (__bf16)exp2f(st[2 * kk + (j >> 2)][m][j & 3]);
#pragma unroll
            for (int dn = 0; dn < 4; ++dn)
                vf[dn] = *(const bf16x8*)&VsB[(dn * 16 + lm) * 64 + (((kk * 4 + lk) ^ (lm & 7)) * 8)];
            __builtin_amdgcn_s_setprio(1);
#pragma unroll
            for (int m = 0; m < 2; ++m)
                o_s[m] = __builtin_amdgcn_mfma_f32_16x16x32_bf16(pa[m], ones, o_s[m], 0, 0, 0);
#pragma unroll
            for (int m = 0; m < 2; ++m)
#pragma unroll
                for (int dn = 0; dn < 4; ++dn)
                    o[m][dn] = __builtin_amdgcn_mfma_f32_16x16x32_bf16(pa[m], vf[dn], o[m][dn], 0, 0, 0);
            __builtin_amdgcn_s_setprio(0);
        }

        if (it + 1 < NT) { FA_WRITE(buf ^ 1); }        // lands in the other buffer
        __syncthreads();                               // one barrier per tile
    }

    if constexpr (NZ == 2) {
        // write unnormalized fp32 partials + rowsums
        float* pod = po + (size_t)blockIdx.z * ((size_t)BB * SQ * DD);
        float* psd = ps + (size_t)blockIdx.z * (BB * HH * SQ) + (size_t)bh * SQ;
#pragma unroll
        for (int m = 0; m < 2; ++m) {
#pragma unroll
            for (int dn = 0; dn < 4; ++dn)
#pragma unroll
                for (int r = 0; r < 4; ++r) {
                    int row = q0 + w * 32 + m * 16 + lk * 4 + r;
                    int col = h * HS + dn * 16 + lm;
                    pod[(size_t)(b * SQ + row) * DD + col] = o[m][dn][r];
                }
            if (lm == 0) {
#pragma unroll
                for (int r = 0; r < 4; ++r)
                    psd[q0 + w * 32 + m * 16 + lk * 4 + r] = o_s[m][r];
            }
        }
    } else {
        // epilogue: o_s[m][r] holds rowsum(q = m*16 + lk*4 + r) at every lm lane
#pragma unroll
        for (int m = 0; m < 2; ++m) {
            f32x4 inv;
#pragma unroll
            for (int r = 0; r < 4; ++r) inv[r] = 1.f / o_s[m][r];
#pragma unroll
            for (int dn = 0; dn < 4; ++dn)
#pragma unroll
                for (int r = 0; r < 4; ++r) {
                    int row = q0 + w * 32 + m * 16 + lk * 4 + r;
                    int col = h * HS + dn * 16 + lm;
                    O[(size_t)(b * SQ + row) * DD + col] = (__bf16)(o[m][dn][r] * inv[r]);
                }
        }
    }
}

// ------------- combine: attb = (po0 + po1) / (ps0 + ps1), bf16 -------------
__global__ void combine2(const float* __restrict__ po, const float* __restrict__ ps,
                         __bf16* __restrict__ O) {
    const size_t PO_Z = (size_t)BB * SQ * DD;
    const int PS_Z = BB * HH * SQ;
    size_t i = (size_t)blockIdx.x * blockDim.x + threadIdx.x;   // one thread per 8 elems
    size_t e = i * 8;
    int rowq = (int)(e >> 10);           // b*SQ + q
    int col = (int)(e & 1023);
    int b = rowq >> 11, q = rowq & 2047, h = col >> 6;
    int psi = (b * HH + h) * SQ + q;
    float inv = 1.f / (ps[psi] + ps[PS_Z + psi]);
    float4 a0 = *(const float4*)&po[e],     a1 = *(const float4*)&po[e + 4];
    float4 b0 = *(const float4*)&po[PO_Z + e], b1 = *(const float4*)&po[PO_Z + e + 4];
    bf16x8 v = {(__bf16)((a0.x + b0.x) * inv), (__bf16)((a0.y + b0.y) * inv),
                (__bf16)((a0.z + b0.z) * inv), (__bf16)((a0.w + b0.w) * inv),
                (__bf16)((a1.x + b1.x) * inv), (__bf16)((a1.y + b1.y) * inv),
                (__bf16)((a1.z + b1.z) * inv), (__bf16)((a1.w + b1.w) * inv)};
    *(bf16x8*)&O[e] = v;
}

extern "C" void kernel_launch(void* const* d_in, const int* in_sizes, int n_in,
                              void* d_out, int out_size, void* d_ws, size_t ws_size,
                              hipStream_t stream) {
    const float* inputs  = (const float*)d_in[0];
    const float* context = (const float*)d_in[1];
    const float* Wq = (const float*)d_in[2];
    const float* bq = (const float*)d_in[3];
    const float* Wk = (const float*)d_in[4];
    const float* bk = (const float*)d_in[5];
    const float* Wv = (const float*)d_in[6];
    const float* bv = (const float*)d_in[7];
    const float* Wo = (const float*)d_in[8];
    const float* bo = (const float*)d_in[9];
    float* out = (float*)d_out;

    char* ws = (char*)d_ws;
    const size_t SEG = (size_t)4096 * 1024 * sizeof(__bf16);  // 8 MB
    __bf16* inA  = (__bf16*)(ws + 0 * SEG);
    __bf16* ctxB = (__bf16*)(ws + 1 * SEG);
    __bf16* Wt   = (__bf16*)(ws + 2 * SEG);   // 4 x 1024x1024 bf16
    __bf16* Qb   = (__bf16*)(ws + 3 * SEG);
    __bf16* Kbuf = (__bf16*)(ws + 4 * SEG);
    __bf16* Vtb  = (__bf16*)(ws + 5 * SEG);   // V transposed + sigma-permuted by gemm_qkv
    __bf16* attb = ctxB;                      // context_bf16 dead after QKV GEMM

    const size_t PO_BYTES = (size_t)2 * BB * SQ * DD * sizeof(float);   // 32 MB
    const size_t PS_BYTES = (size_t)2 * BB * HH * SQ * sizeof(float);   // 512 KB
    float* po = (float*)(ws + 6 * SEG);
    float* ps = (float*)(ws + 6 * SEG + PO_BYTES);
    bool split = ws_size >= 6 * SEG + PO_BYTES + PS_BYTES;

    int n8 = 4096 * 1024 / 8;
    cast2_f32_bf16<<<2 * n8 / 256, 256, 0, stream>>>(inputs, context, inA, ctxB, n8);
    wtrans<<<dim3(32, 32, 4), dim3(32, 8), 0, stream>>>(Wq, Wk, Wv, Wo, Wt);

    gemm_qkv<<<dim3(8, 32, 3), 256, 0, stream>>>(inA, ctxB, Wt, bq, bk, bv,
                                                 Qb, Kbuf, Vtb, SCALE * LOG2E);

    if (split) {
        flash_attn<2><<<dim3(16, 32, 2), 256, 0, stream>>>(Qb, Kbuf, Vtb, attb, po, ps);
        combine2<<<(BB * SQ * DD / 8) / 256, 256, 0, stream>>>(po, ps, attb);
    } else {
        flash_attn<1><<<dim3(16, 32), 256, 0, stream>>>(Qb, Kbuf, Vtb, attb, nullptr, nullptr);
    }

    gemm_out64<<<dim3(8, 64), 256, 0, stream>>>(attb, Wt + (size_t)3 * DD * DD, bo, out);
}

// Round 10
// 134.462 us; speedup vs baseline: 1.1895x; 1.1895x over previous
//
#include <hip/hip_runtime.h>

// Problem constants
#define BB 2
#define SQ 2048
#define SK 2048
#define DD 1024
#define HH 16
#define HS 64
#define SCALE 0.125f
#define LOG2E 1.4426950408889634f

typedef __bf16 bf16x8 __attribute__((ext_vector_type(8)));
typedef float f32x4 __attribute__((ext_vector_type(4)));
typedef unsigned int uint;

// Fast hardware exp2: exp2f without -ffast-math lowers to the precise OCML path
// (~20 VALU instrs). v_exp_f32 is 1 quarter-rate instr, <=1 ULP -- plenty for bf16.
#if defined(__has_builtin)
#if __has_builtin(__builtin_amdgcn_exp2f)
#define FEXP2(x) __builtin_amdgcn_exp2f(x)
#endif
#endif
#ifndef FEXP2
extern "C" __device__ float __ocml_native_exp2_f32(float);
#define FEXP2(x) __ocml_native_exp2_f32(x)
#endif

__device__ __forceinline__ void gload_lds16(const __bf16* g, __bf16* l) {
    __builtin_amdgcn_global_load_lds((const __attribute__((address_space(1))) uint*)(g),
                                     (__attribute__((address_space(3))) uint*)(l), 16, 0, 0);
}

// ---------------- cast fp32 -> bf16 (both inputs in one launch) ----------------
__global__ void cast2_f32_bf16(const float* __restrict__ in0, const float* __restrict__ in1,
                               __bf16* __restrict__ out0, __bf16* __restrict__ out1, int n8each) {
    int i = blockIdx.x * blockDim.x + threadIdx.x;
    const float* src;
    __bf16* dst;
    int j;
    if (i < n8each) { src = in0; dst = out0; j = i; }
    else            { src = in1; dst = out1; j = i - n8each; }
    const float4* p = ((const float4*)src) + (size_t)j * 2;
    float4 a = p[0], b = p[1];
    bf16x8 v = {(__bf16)a.x, (__bf16)a.y, (__bf16)a.z, (__bf16)a.w,
                (__bf16)b.x, (__bf16)b.y, (__bf16)b.z, (__bf16)b.w};
    ((bf16x8*)dst)[j] = v;
}

// ------------- cast+transpose the 4 weight matrices [K][N] -> bf16 [N][K] -------------
__global__ void wtrans(const float* __restrict__ W0, const float* __restrict__ W1,
                       const float* __restrict__ W2, const float* __restrict__ W3,
                       __bf16* __restrict__ Wt) {
    __shared__ __bf16 tile[32][33];
    const float* W = blockIdx.z == 0 ? W0 : blockIdx.z == 1 ? W1 : blockIdx.z == 2 ? W2 : W3;
    __bf16* out = Wt + (size_t)blockIdx.z * DD * DD;
    int tx = threadIdx.x, ty = threadIdx.y;     // (32, 8)
    int k0 = blockIdx.y * 32, n0 = blockIdx.x * 32;
#pragma unroll
    for (int j = 0; j < 4; ++j)
        tile[ty + j * 8][tx] = (__bf16)W[(size_t)(k0 + ty + j * 8) * DD + n0 + tx];
    __syncthreads();
#pragma unroll
    for (int j = 0; j < 4; ++j)
        out[(size_t)(n0 + ty + j * 8) * DD + k0 + tx] = tile[tx][ty + j * 8];
}

// ------------- GEMM body: acc = A[4096,1024] @ Bt[1024,1024]^T -------------
// 128x128 tile, BK=64, 256 threads (4 waves, 64x64 quadrant each), global_load_lds staging
// MODE 0: C = bf16 (acc+bias)*scale ; MODE 2: transposed + kv-bit-permuted Vt write
#define BM 128
#define BN 128
#define BK 64
template <int MODE>
__device__ __forceinline__ void gemm_body(const __bf16* __restrict__ A, const __bf16* __restrict__ Bt,
                                          const float* __restrict__ bias, void* __restrict__ Cout,
                                          float scale) {
    __shared__ __bf16 As[BM][BK];
    __shared__ __bf16 Bs[BN][BK];
    int t = threadIdx.x;
    int w = t >> 6, l = t & 63;
    int lm = l & 15, lk = l >> 4;
    int wr = w >> 1, wc = w & 1;
    int br = blockIdx.y, bc = blockIdx.x;
    int srow = (l >> 3), scol = (l & 7) * 8;
    f32x4 acc[4][4] = {};
    for (int kt = 0; kt < 1024; kt += BK) {
        __syncthreads();
#pragma unroll
        for (int j = 0; j < 4; ++j) {
            int r0 = (w * 4 + j) * 8;
            gload_lds16(&A[(size_t)(br * BM + r0 + srow) * 1024 + kt + scol], &As[r0][0]);
            gload_lds16(&Bt[(size_t)(bc * BN + r0 + srow) * 1024 + kt + scol], &Bs[r0][0]);
        }
        __syncthreads();
#pragma unroll
        for (int kk = 0; kk < BK; kk += 32) {
            bf16x8 af[4], bf[4];
#pragma unroll
            for (int m = 0; m < 4; ++m) af[m] = *(const bf16x8*)&As[wr * 64 + m * 16 + lm][kk + lk * 8];
#pragma unroll
            for (int n = 0; n < 4; ++n) bf[n] = *(const bf16x8*)&Bs[wc * 64 + n * 16 + lm][kk + lk * 8];
#pragma unroll
            for (int m = 0; m < 4; ++m)
#pragma unroll
                for (int n = 0; n < 4; ++n)
                    acc[m][n] = __builtin_amdgcn_mfma_f32_16x16x32_bf16(af[m], bf[n], acc[m][n], 0, 0, 0);
        }
    }
#pragma unroll
    for (int m = 0; m < 4; ++m)
#pragma unroll
        for (int n = 0; n < 4; ++n) {
            int col = bc * BN + wc * 64 + n * 16 + lm;
            float bv = bias[col];
            if constexpr (MODE == 2) {
                // Vt value for key-pos sk stored at sigma-permuted position:
                // within 64-block: p = o5<<5 | o3<<4 | o2<<3 | o4<<2 | o1o0  (o = sk & 63)
                int row = br * BM + wr * 64 + m * 16 + lk * 4;   // sk0 (multiple of 4)
                int b_ = row >> 11, sk = row & 2047;
                int skb = sk & ~63, o = sk & 63;
                int p0 = (o & 32) | (((o >> 3) & 1) << 4) | (((o >> 2) & 1) << 3) | (((o >> 4) & 1) << 2);
                int h_ = col >> 6, d_ = col & 63;
                union { ushort4 u; __bf16 h[4]; } pk;
#pragma unroll
                for (int r = 0; r < 4; ++r) pk.h[r] = (__bf16)(acc[m][n][r] + bv);
                *(ushort4*)((__bf16*)Cout + ((size_t)((b_ * 16 + h_) * 64 + d_) * 2048 + skb + p0)) = pk.u;
            } else {
#pragma unroll
                for (int r = 0; r < 4; ++r) {
                    int row = br * BM + wr * 64 + m * 16 + lk * 4 + r;
                    ((__bf16*)Cout)[(size_t)row * 1024 + col] = (__bf16)((acc[m][n][r] + bv) * scale);
                }
            }
        }
}

// fused Q/K/V projections: z==0 -> Q (scaled), z==1 -> K, z==2 -> V written transposed+permuted as Vt
__global__ __launch_bounds__(256) void gemm_qkv(const __bf16* __restrict__ Ain, const __bf16* __restrict__ Actx,
                                                const __bf16* __restrict__ Wt,
                                                const float* __restrict__ bq, const float* __restrict__ bk,
                                                const float* __restrict__ bv,
                                                __bf16* __restrict__ Qb, __bf16* __restrict__ Kb,
                                                __bf16* __restrict__ Vtb, float qscale) {
    int z = blockIdx.z;
    const __bf16* A = (z == 0) ? Ain : Actx;
    const __bf16* B = Wt + (size_t)z * DD * DD;
    if (z == 0)      gemm_body<0>(A, B, bq, Qb, qscale);
    else if (z == 1) gemm_body<0>(A, B, bk, Kb, 1.f);
    else             gemm_body<2>(A, B, bv, Vtb, 1.f);
}

// ------------- output GEMM: 64x128 tile (grid 512 = 2 blocks/CU), float out -------------
__global__ __launch_bounds__(256) void gemm_out64(const __bf16* __restrict__ A, const __bf16* __restrict__ Bt,
                                                  const float* __restrict__ bias, float* __restrict__ C) {
    __shared__ __bf16 As[64][64];
    __shared__ __bf16 Bs[128][64];
    int t = threadIdx.x;
    int w = t >> 6, l = t & 63;
    int lm = l & 15, lk = l >> 4;
    int br = blockIdx.y, bc = blockIdx.x;   // grid (8, 64)
    int srow = (l >> 3), scol = (l & 7) * 8;
    f32x4 acc[4][2] = {};
    for (int kt = 0; kt < 1024; kt += 64) {
        __syncthreads();
#pragma unroll
        for (int j = 0; j < 2; ++j) {
            int r0 = (j * 4 + w) * 8;
            gload_lds16(&A[(size_t)(br * 64 + r0 + srow) * 1024 + kt + scol], &As[r0][0]);
        }
#pragma unroll
        for (int j = 0; j < 4; ++j) {
            int r0 = (j * 4 + w) * 8;
            gload_lds16(&Bt[(size_t)(bc * 128 + r0 + srow) * 1024 + kt + scol], &Bs[r0][0]);
        }
        __syncthreads();
#pragma unroll
        for (int kk = 0; kk < 64; kk += 32) {
            bf16x8 af[4], bf[2];
#pragma unroll
            for (int m = 0; m < 4; ++m) af[m] = *(const bf16x8*)&As[m * 16 + lm][kk + lk * 8];
#pragma unroll
            for (int n = 0; n < 2; ++n) bf[n] = *(const bf16x8*)&Bs[w * 32 + n * 16 + lm][kk + lk * 8];
#pragma unroll
            for (int m = 0; m < 4; ++m)
#pragma unroll
                for (int n = 0; n < 2; ++n)
                    acc[m][n] = __builtin_amdgcn_mfma_f32_16x16x32_bf16(af[m], bf[n], acc[m][n], 0, 0, 0);
        }
    }
#pragma unroll
    for (int m = 0; m < 4; ++m)
#pragma unroll
        for (int n = 0; n < 2; ++n) {
            int col = bc * 128 + w * 32 + n * 16 + lm;
            float bv = bias[col];
#pragma unroll
            for (int r = 0; r < 4; ++r) {
                int row = br * 64 + m * 16 + lk * 4 + r;
                C[(size_t)row * 1024 + col] = acc[m][n][r] + bv;
            }
        }
}

// ------------- flash attention, swapped-QK^T (S^T), lane-local P -------------
// QBLK=128: 4 waves x 32 q-rows; KVBLK=64, double-buffered K/V, 1 barrier/tile.
// V's kv-permutation sigma baked into Vt's GLOBAL layout (gemm_qkv MODE 2).
// Hoisted addressing: per-lane swizzled LDS offsets o0/o1 precomputed (reads become
// base + compile-time imm); global staging via 4 advancing pointers.
// Row-sums via extra MFMA against all-ones B. Fast HW exp2 (FEXP2).
__global__ __launch_bounds__(256) void flash_attn(const __bf16* __restrict__ Q,
                                                  const __bf16* __restrict__ Kb,
                                                  const __bf16* __restrict__ Vt,
                                                  __bf16* __restrict__ O) {
    __shared__ __bf16 Ks[2][64 * 64];
    __shared__ __bf16 Vs[2][64 * 64];
    int t = threadIdx.x, w = t >> 6, l = t & 63;
    int lm = l & 15, lk = l >> 4;
    int bh = blockIdx.y, b = bh >> 4, h = bh & 15;
    int q0 = blockIdx.x * 128;

    // Q fragments straight from global (one-time): wave w owns q rows q0+w*32 .. +31
    bf16x8 qf[2][2];
#pragma unroll
    for (int m = 0; m < 2; ++m)
#pragma unroll
        for (int kk = 0; kk < 2; ++kk)
            qf[m][kk] = *(const bf16x8*)&Q[(size_t)(b * SQ + q0 + w * 32 + m * 16 + lm) * DD + h * HS + kk * 32 + lk * 8];

    // staging geometry: thread covers rows r0 and r0+32, 8-elem chunk c8; swizzled chunk c8^(r0&7)
    int r0 = t >> 3, c8 = t & 7;
    int chs = c8 ^ (r0 & 7);
    __bf16* ksl0 = &Ks[0][(r0)      * 64 + chs * 8];
    __bf16* ksl1 = &Ks[0][(r0 + 32) * 64 + chs * 8];
    __bf16* vsl0 = &Vs[0][(r0)      * 64 + chs * 8];
    __bf16* vsl1 = &Vs[0][(r0 + 32) * 64 + chs * 8];

    // advancing global pointers (K: +64 rows/tile; V: +64 cols/tile)
    const __bf16* kp0 = Kb + (size_t)b * SK * DD + h * HS + (size_t)r0 * DD + c8 * 8;
    const __bf16* kp1 = kp0 + (size_t)32 * DD;
    const __bf16* vp0 = Vt + (size_t)bh * HS * SK + (size_t)r0 * SK + c8 * 8;
    const __bf16* vp1 = vp0 + (size_t)32 * SK;

    // per-lane swizzled LDS read offsets (elements): row term lm*64 folded in
    int o0 = lm * 64 + ((lk ^ (lm & 7)) * 8);
    int o1 = lm * 64 + (((4 + lk) ^ (lm & 7)) * 8);

    float4 kr0, kr1, vr0, vr1;   // NAMED regs only (arrays -> scratch)
#define FA_LOAD()                                                                \
    kr0 = *(const float4*)kp0; kr1 = *(const float4*)kp1;                        \
    vr0 = *(const float4*)vp0; vr1 = *(const float4*)vp1;                        \
    kp0 += (size_t)64 * DD; kp1 += (size_t)64 * DD; vp0 += 64; vp1 += 64;
#define FA_WRITE(BUF)                                                            \
    *(float4*)(ksl0 + (BUF) * 4096) = kr0;                                       \
    *(float4*)(ksl1 + (BUF) * 4096) = kr1;                                       \
    *(float4*)(vsl0 + (BUF) * 4096) = vr0;                                       \
    *(float4*)(vsl1 + (BUF) * 4096) = vr1;

    FA_LOAD();
    FA_WRITE(0);
    __syncthreads();

    bf16x8 ones;
#pragma unroll
    for (int j = 0; j < 8; ++j) ones[j] = (__bf16)1.0f;

    f32x4 o[2][4] = {};
    f32x4 o_s[2] = {};

    for (int it = 0; it < 32; ++it) {
        int buf = it & 1;
        if (it + 1 < 32) { FA_LOAD(); }   // issue early; hides under compute

        const __bf16* KsB = &Ks[buf][0];
        const __bf16* VsB = &Vs[buf][0];

        // S^T = K Q^T : st[n][m], lane holds P[q=m*16+lm][kv=16n+4lk+r]
        f32x4 st[4][2] = {};
        __builtin_amdgcn_s_setprio(1);
#pragma unroll
        for (int kk = 0; kk < 2; ++kk) {
#pragma unroll
            for (int n = 0; n < 4; ++n) {
                bf16x8 kf = *(const bf16x8*)&KsB[(kk ? o1 : o0) + n * 1024];
#pragma unroll
                for (int m = 0; m < 2; ++m)
                    st[n][m] = __builtin_amdgcn_mfma_f32_16x16x32_bf16(kf, qf[m][kk], st[n][m], 0, 0, 0);
            }
        }
        __builtin_amdgcn_s_setprio(0);

        // P = exp2(S) fused into fragment assembly; PV + ones-column row-sum
#pragma unroll
        for (int kk = 0; kk < 2; ++kk) {
            bf16x8 pa[2], vf[4];
#pragma unroll
            for (int m = 0; m < 2; ++m)
#pragma unroll
                for (int j = 0; j < 8; ++j)
                    pa[m][j] = (__bf16)FEXP2(st[2 * kk + (j >> 2)][m][j & 3]);
#pragma unroll
            for (int dn = 0; dn < 4; ++dn)
                vf[dn] = *(const bf16x8*)&VsB[(kk ? o1 : o0) + dn * 1024];
            __builtin_amdgcn_s_setprio(1);
#pragma unroll
            for (int m = 0; m < 2; ++m)
                o_s[m] = __builtin_amdgcn_mfma_f32_16x16x32_bf16(pa[m], ones, o_s[m], 0, 0, 0);
#pragma unroll
            for (int m = 0; m < 2; ++m)
#pragma unroll
                for (int dn = 0; dn < 4; ++dn)
                    o[m][dn] = __builtin_amdgcn_mfma_f32_16x16x32_bf16(pa[m], vf[dn], o[m][dn], 0, 0, 0);
            __builtin_amdgcn_s_setprio(0);
        }

        if (it + 1 < 32) { FA_WRITE(buf ^ 1); }        // lands in the other buffer
        __syncthreads();                               // one barrier per tile
    }

    // epilogue: o_s[m][r] holds rowsum(q = m*16 + lk*4 + r) at every lm lane
#pragma unroll
    for (int m = 0; m < 2; ++m) {
        f32x4 inv;
#pragma unroll
        for (int r = 0; r < 4; ++r) inv[r] = 1.f / o_s[m][r];
#pragma unroll
        for (int dn = 0; dn < 4; ++dn)
#pragma unroll
            for (int r = 0; r < 4; ++r) {
                int row = q0 + w * 32 + m * 16 + lk * 4 + r;
                int col = h * HS + dn * 16 + lm;
                O[(size_t)(b * SQ + row) * DD + col] = (__bf16)(o[m][dn][r] * inv[r]);
            }
    }
}

extern "C" void kernel_launch(void* const* d_in, const int* in_sizes, int n_in,
                              void* d_out, int out_size, void* d_ws, size_t ws_size,
                              hipStream_t stream) {
    const float* inputs  = (const float*)d_in[0];
    const float* context = (const float*)d_in[1];
    const float* Wq = (const float*)d_in[2];
    const float* bq = (const float*)d_in[3];
    const float* Wk = (const float*)d_in[4];
    const float* bk = (const float*)d_in[5];
    const float* Wv = (const float*)d_in[6];
    const float* bv = (const float*)d_in[7];
    const float* Wo = (const float*)d_in[8];
    const float* bo = (const float*)d_in[9];
    float* out = (float*)d_out;

    char* ws = (char*)d_ws;
    const size_t SEG = (size_t)4096 * 1024 * sizeof(__bf16);  // 8 MB
    __bf16* inA  = (__bf16*)(ws + 0 * SEG);
    __bf16* ctxB = (__bf16*)(ws + 1 * SEG);
    __bf16* Wt   = (__bf16*)(ws + 2 * SEG);   // 4 x 1024x1024 bf16
    __bf16* Qb   = (__bf16*)(ws + 3 * SEG);
    __bf16* Kbuf = (__bf16*)(ws + 4 * SEG);
    __bf16* Vtb  = (__bf16*)(ws + 5 * SEG);   // V transposed + sigma-permuted by gemm_qkv
    __bf16* attb = ctxB;                      // context_bf16 dead after QKV GEMM

    int n8 = 4096 * 1024 / 8;
    cast2_f32_bf16<<<2 * n8 / 256, 256, 0, stream>>>(inputs, context, inA, ctxB, n8);
    wtrans<<<dim3(32, 32, 4), dim3(32, 8), 0, stream>>>(Wq, Wk, Wv, Wo, Wt);

    gemm_qkv<<<dim3(8, 32, 3), 256, 0, stream>>>(inA, ctxB, Wt, bq, bk, bv,
                                                 Qb, Kbuf, Vtb, SCALE * LOG2E);

    flash_attn<<<dim3(16, 32), 256, 0, stream>>>(Qb, Kbuf, Vtb, attb);

    gemm_out64<<<dim3(8, 64), 256, 0, stream>>>(attb, Wt + (size_t)3 * DD * DD, bo, out);
}

// Round 11
// 134.458 us; speedup vs baseline: 1.1895x; 1.0000x over previous
//
#include <hip/hip_runtime.h>

// Problem constants
#define BB 2
#define SQ 2048
#define SK 2048
#define DD 1024
#define HH 16
#define HS 64
#define SCALE 0.125f
#define LOG2E 1.4426950408889634f

typedef __bf16 bf16x8 __attribute__((ext_vector_type(8)));
typedef float f32x4 __attribute__((ext_vector_type(4)));
typedef unsigned int uint;

// Fast hardware exp2 (exp2f without -ffast-math lowers to the ~20-instr OCML path)
#if defined(__has_builtin)
#if __has_builtin(__builtin_amdgcn_exp2f)
#define FEXP2(x) __builtin_amdgcn_exp2f(x)
#endif
#endif
#ifndef FEXP2
extern "C" __device__ float __ocml_native_exp2_f32(float);
#define FEXP2(x) __ocml_native_exp2_f32(x)
#endif

__device__ __forceinline__ void gload_lds16(const __bf16* g, __bf16* l) {
    __builtin_amdgcn_global_load_lds((const __attribute__((address_space(1))) uint*)(g),
                                     (__attribute__((address_space(3))) uint*)(l), 16, 0, 0);
}

// ---------------- cast fp32 -> bf16 (both inputs in one launch) ----------------
__global__ void cast2_f32_bf16(const float* __restrict__ in0, const float* __restrict__ in1,
                               __bf16* __restrict__ out0, __bf16* __restrict__ out1, int n8each) {
    int i = blockIdx.x * blockDim.x + threadIdx.x;
    const float* src;
    __bf16* dst;
    int j;
    if (i < n8each) { src = in0; dst = out0; j = i; }
    else            { src = in1; dst = out1; j = i - n8each; }
    const float4* p = ((const float4*)src) + (size_t)j * 2;
    float4 a = p[0], b = p[1];
    bf16x8 v = {(__bf16)a.x, (__bf16)a.y, (__bf16)a.z, (__bf16)a.w,
                (__bf16)b.x, (__bf16)b.y, (__bf16)b.z, (__bf16)b.w};
    ((bf16x8*)dst)[j] = v;
}

// ------------- cast+transpose the 4 weight matrices [K][N] -> bf16 [N][K] -------------
__global__ void wtrans(const float* __restrict__ W0, const float* __restrict__ W1,
                       const float* __restrict__ W2, const float* __restrict__ W3,
                       __bf16* __restrict__ Wt) {
    __shared__ __bf16 tile[32][33];
    const float* W = blockIdx.z == 0 ? W0 : blockIdx.z == 1 ? W1 : blockIdx.z == 2 ? W2 : W3;
    __bf16* out = Wt + (size_t)blockIdx.z * DD * DD;
    int tx = threadIdx.x, ty = threadIdx.y;     // (32, 8)
    int k0 = blockIdx.y * 32, n0 = blockIdx.x * 32;
#pragma unroll
    for (int j = 0; j < 4; ++j)
        tile[ty + j * 8][tx] = (__bf16)W[(size_t)(k0 + ty + j * 8) * DD + n0 + tx];
    __syncthreads();
#pragma unroll
    for (int j = 0; j < 4; ++j)
        out[(size_t)(n0 + ty + j * 8) * DD + k0 + tx] = tile[tx][ty + j * 8];
}

// ------------- GEMM body: acc = A[4096,1024] @ Bt[1024,1024]^T -------------
// 128x128 tile, BK=64, 256 threads (4 waves, 64x64 quadrant each), global_load_lds staging.
// LDS tiles are passed IN (declared once per kernel) so multiple template instantiations
// in one kernel share one 32 KB allocation (round-10 lesson: per-instantiation static
// __shared__ doubled LDS to 64 KB -> 2 blocks/CU occupancy cap).
// MODE 0: C = bf16 (acc+bias)*scale ; MODE 2: transposed + kv-bit-permuted Vt write
#define BM 128
#define BN 128
#define BK 64
template <int MODE>
__device__ __forceinline__ void gemm_body(__bf16 (* __restrict__ As)[BK], __bf16 (* __restrict__ Bs)[BK],
                                          const __bf16* __restrict__ A, const __bf16* __restrict__ Bt,
                                          const float* __restrict__ bias, void* __restrict__ Cout,
                                          float scale) {
    int t = threadIdx.x;
    int w = t >> 6, l = t & 63;
    int lm = l & 15, lk = l >> 4;
    int wr = w >> 1, wc = w & 1;
    int br = blockIdx.y, bc = blockIdx.x;
    int srow = (l >> 3), scol = (l & 7) * 8;
    f32x4 acc[4][4] = {};
    for (int kt = 0; kt < 1024; kt += BK) {
        __syncthreads();
#pragma unroll
        for (int j = 0; j < 4; ++j) {
            int r0 = (w * 4 + j) * 8;
            gload_lds16(&A[(size_t)(br * BM + r0 + srow) * 1024 + kt + scol], &As[r0][0]);
            gload_lds16(&Bt[(size_t)(bc * BN + r0 + srow) * 1024 + kt + scol], &Bs[r0][0]);
        }
        __syncthreads();
#pragma unroll
        for (int kk = 0; kk < BK; kk += 32) {
            bf16x8 af[4], bf[4];
#pragma unroll
            for (int m = 0; m < 4; ++m) af[m] = *(const bf16x8*)&As[wr * 64 + m * 16 + lm][kk + lk * 8];
#pragma unroll
            for (int n = 0; n < 4; ++n) bf[n] = *(const bf16x8*)&Bs[wc * 64 + n * 16 + lm][kk + lk * 8];
#pragma unroll
            for (int m = 0; m < 4; ++m)
#pragma unroll
                for (int n = 0; n < 4; ++n)
                    acc[m][n] = __builtin_amdgcn_mfma_f32_16x16x32_bf16(af[m], bf[n], acc[m][n], 0, 0, 0);
        }
    }
#pragma unroll
    for (int m = 0; m < 4; ++m)
#pragma unroll
        for (int n = 0; n < 4; ++n) {
            int col = bc * BN + wc * 64 + n * 16 + lm;
            float bv = bias[col];
            if constexpr (MODE == 2) {
                // Vt value for key-pos sk stored at sigma-permuted position:
                // within 64-block: p = o5<<5 | o3<<4 | o2<<3 | o4<<2 | o1o0  (o = sk & 63)
                int row = br * BM + wr * 64 + m * 16 + lk * 4;   // sk0 (multiple of 4)
                int b_ = row >> 11, sk = row & 2047;
                int skb = sk & ~63, o = sk & 63;
                int p0 = (o & 32) | (((o >> 3) & 1) << 4) | (((o >> 2) & 1) << 3) | (((o >> 4) & 1) << 2);
                int h_ = col >> 6, d_ = col & 63;
                union { ushort4 u; __bf16 h[4]; } pk;
#pragma unroll
                for (int r = 0; r < 4; ++r) pk.h[r] = (__bf16)(acc[m][n][r] + bv);
                *(ushort4*)((__bf16*)Cout + ((size_t)((b_ * 16 + h_) * 64 + d_) * 2048 + skb + p0)) = pk.u;
            } else {
#pragma unroll
                for (int r = 0; r < 4; ++r) {
                    int row = br * BM + wr * 64 + m * 16 + lk * 4 + r;
                    ((__bf16*)Cout)[(size_t)row * 1024 + col] = (__bf16)((acc[m][n][r] + bv) * scale);
                }
            }
        }
}

// fused Q/K/V projections: z==0 -> Q (scaled), z==1 -> K, z==2 -> V written transposed+permuted as Vt
__global__ __launch_bounds__(256) void gemm_qkv(const __bf16* __restrict__ Ain, const __bf16* __restrict__ Actx,
                                                const __bf16* __restrict__ Wt,
                                                const float* __restrict__ bq, const float* __restrict__ bk,
                                                const float* __restrict__ bv,
                                                __bf16* __restrict__ Qb, __bf16* __restrict__ Kb,
                                                __bf16* __restrict__ Vtb, float qscale) {
    __shared__ __bf16 As[BM][BK];
    __shared__ __bf16 Bs[BN][BK];
    int z = blockIdx.z;
    const __bf16* A = (z == 0) ? Ain : Actx;
    const __bf16* B = Wt + (size_t)z * DD * DD;
    if (z == 0)      gemm_body<0>(As, Bs, A, B, bq, Qb, qscale);
    else if (z == 1) gemm_body<0>(As, Bs, A, B, bk, Kb, 1.f);
    else             gemm_body<2>(As, Bs, A, B, bv, Vtb, 1.f);
}

// ------------- output GEMM: 64x128 tile (grid 512 = 2 blocks/CU), float out -------------
__global__ __launch_bounds__(256) void gemm_out64(const __bf16* __restrict__ A, const __bf16* __restrict__ Bt,
                                                  const float* __restrict__ bias, float* __restrict__ C) {
    __shared__ __bf16 As[64][64];
    __shared__ __bf16 Bs[128][64];
    int t = threadIdx.x;
    int w = t >> 6, l = t & 63;
    int lm = l & 15, lk = l >> 4;
    int br = blockIdx.y, bc = blockIdx.x;   // grid (8, 64)
    int srow = (l >> 3), scol = (l & 7) * 8;
    f32x4 acc[4][2] = {};
    for (int kt = 0; kt < 1024; kt += 64) {
        __syncthreads();
#pragma unroll
        for (int j = 0; j < 2; ++j) {
            int r0 = (j * 4 + w) * 8;
            gload_lds16(&A[(size_t)(br * 64 + r0 + srow) * 1024 + kt + scol], &As[r0][0]);
        }
#pragma unroll
        for (int j = 0; j < 4; ++j) {
            int r0 = (j * 4 + w) * 8;
            gload_lds16(&Bt[(size_t)(bc * 128 + r0 + srow) * 1024 + kt + scol], &Bs[r0][0]);
        }
        __syncthreads();
#pragma unroll
        for (int kk = 0; kk < 64; kk += 32) {
            bf16x8 af[4], bf[2];
#pragma unroll
            for (int m = 0; m < 4; ++m) af[m] = *(const bf16x8*)&As[m * 16 + lm][kk + lk * 8];
#pragma unroll
            for (int n = 0; n < 2; ++n) bf[n] = *(const bf16x8*)&Bs[w * 32 + n * 16 + lm][kk + lk * 8];
#pragma unroll
            for (int m = 0; m < 4; ++m)
#pragma unroll
                for (int n = 0; n < 2; ++n)
                    acc[m][n] = __builtin_amdgcn_mfma_f32_16x16x32_bf16(af[m], bf[n], acc[m][n], 0, 0, 0);
        }
    }
#pragma unroll
    for (int m = 0; m < 4; ++m)
#pragma unroll
        for (int n = 0; n < 2; ++n) {
            int col = bc * 128 + w * 32 + n * 16 + lm;
            float bv = bias[col];
#pragma unroll
            for (int r = 0; r < 4; ++r) {
                int row = br * 64 + m * 16 + lk * 4 + r;
                C[(size_t)row * 1024 + col] = acc[m][n][r] + bv;
            }
        }
}

// ------------- flash attention, swapped-QK^T (S^T), lane-local P -------------
// QBLK=128: 4 waves x 32 q-rows; KVBLK=64, double-buffered K/V, 1 barrier/tile.
// V's kv-permutation sigma baked into Vt's GLOBAL layout (gemm_qkv MODE 2).
// Hoisted addressing; advancing global pointers; ones-MFMA row-sums; HW exp2.
__global__ __launch_bounds__(256) void flash_attn(const __bf16* __restrict__ Q,
                                                  const __bf16* __restrict__ Kb,
                                                  const __bf16* __restrict__ Vt,
                                                  __bf16* __restrict__ O) {
    __shared__ __bf16 Ks[2][64 * 64];
    __shared__ __bf16 Vs[2][64 * 64];
    int t = threadIdx.x, w = t >> 6, l = t & 63;
    int lm = l & 15, lk = l >> 4;
    int bh = blockIdx.y, b = bh >> 4, h = bh & 15;
    int q0 = blockIdx.x * 128;

    // Q fragments straight from global (one-time): wave w owns q rows q0+w*32 .. +31
    bf16x8 qf[2][2];
#pragma unroll
    for (int m = 0; m < 2; ++m)
#pragma unroll
        for (int kk = 0; kk < 2; ++kk)
            qf[m][kk] = *(const bf16x8*)&Q[(size_t)(b * SQ + q0 + w * 32 + m * 16 + lm) * DD + h * HS + kk * 32 + lk * 8];

    // staging geometry: thread covers rows r0 and r0+32, 8-elem chunk c8; swizzled chunk c8^(r0&7)
    int r0 = t >> 3, c8 = t & 7;
    int chs = c8 ^ (r0 & 7);
    __bf16* ksl0 = &Ks[0][(r0)      * 64 + chs * 8];
    __bf16* ksl1 = &Ks[0][(r0 + 32) * 64 + chs * 8];
    __bf16* vsl0 = &Vs[0][(r0)      * 64 + chs * 8];
    __bf16* vsl1 = &Vs[0][(r0 + 32) * 64 + chs * 8];

    // advancing global pointers (K: +64 rows/tile; V: +64 cols/tile)
    const __bf16* kp0 = Kb + (size_t)b * SK * DD + h * HS + (size_t)r0 * DD + c8 * 8;
    const __bf16* kp1 = kp0 + (size_t)32 * DD;
    const __bf16* vp0 = Vt + (size_t)bh * HS * SK + (size_t)r0 * SK + c8 * 8;
    const __bf16* vp1 = vp0 + (size_t)32 * SK;

    // per-lane swizzled LDS read offsets (elements): row term lm*64 folded in
    int o0 = lm * 64 + ((lk ^ (lm & 7)) * 8);
    int o1 = lm * 64 + (((4 + lk) ^ (lm & 7)) * 8);

    float4 kr0, kr1, vr0, vr1;   // NAMED regs only (arrays -> scratch)
#define FA_LOAD()                                                                \
    kr0 = *(const float4*)kp0; kr1 = *(const float4*)kp1;                        \
    vr0 = *(const float4*)vp0; vr1 = *(const float4*)vp1;                        \
    kp0 += (size_t)64 * DD; kp1 += (size_t)64 * DD; vp0 += 64; vp1 += 64;
#define FA_WRITE(BUF)                                                            \
    *(float4*)(ksl0 + (BUF) * 4096) = kr0;                                       \
    *(float4*)(ksl1 + (BUF) * 4096) = kr1;                                       \
    *(float4*)(vsl0 + (BUF) * 4096) = vr0;                                       \
    *(float4*)(vsl1 + (BUF) * 4096) = vr1;

    FA_LOAD();
    FA_WRITE(0);
    __syncthreads();

    bf16x8 ones;
#pragma unroll
    for (int j = 0; j < 8; ++j) ones[j] = (__bf16)1.0f;

    f32x4 o[2][4] = {};
    f32x4 o_s[2] = {};

    for (int it = 0; it < 32; ++it) {
        int buf = it & 1;
        if (it + 1 < 32) { FA_LOAD(); }   // issue early; hides under compute

        const __bf16* KsB = &Ks[buf][0];
        const __bf16* VsB = &Vs[buf][0];

        // S^T = K Q^T : st[n][m], lane holds P[q=m*16+lm][kv=16n+4lk+r]
        f32x4 st[4][2] = {};
        __builtin_amdgcn_s_setprio(1);
#pragma unroll
        for (int kk = 0; kk < 2; ++kk) {
#pragma unroll
            for (int n = 0; n < 4; ++n) {
                bf16x8 kf = *(const bf16x8*)&KsB[(kk ? o1 : o0) + n * 1024];
#pragma unroll
                for (int m = 0; m < 2; ++m)
                    st[n][m] = __builtin_amdgcn_mfma_f32_16x16x32_bf16(kf, qf[m][kk], st[n][m], 0, 0, 0);
            }
        }
        __builtin_amdgcn_s_setprio(0);

        // P = exp2(S) fused into fragment assembly; PV + ones-column row-sum
#pragma unroll
        for (int kk = 0; kk < 2; ++kk) {
            bf16x8 pa[2], vf[4];
#pragma unroll
            for (int m = 0; m < 2; ++m)
#pragma unroll
                for (int j = 0; j < 8; ++j)
                    pa[m][j] = (__bf16)FEXP2(st[2 * kk + (j >> 2)][m][j & 3]);
#pragma unroll
            for (int dn = 0; dn < 4; ++dn)
                vf[dn] = *(const bf16x8*)&VsB[(kk ? o1 : o0) + dn * 1024];
            __builtin_amdgcn_s_setprio(1);
#pragma unroll
            for (int m = 0; m < 2; ++m)
                o_s[m] = __builtin_amdgcn_mfma_f32_16x16x32_bf16(pa[m], ones, o_s[m], 0, 0, 0);
#pragma unroll
            for (int m = 0; m < 2; ++m)
#pragma unroll
                for (int dn = 0; dn < 4; ++dn)
                    o[m][dn] = __builtin_amdgcn_mfma_f32_16x16x32_bf16(pa[m], vf[dn], o[m][dn], 0, 0, 0);
            __builtin_amdgcn_s_setprio(0);
        }

        if (it + 1 < 32) { FA_WRITE(buf ^ 1); }        // lands in the other buffer
        __syncthreads();                               // one barrier per tile
    }

    // epilogue: o_s[m][r] holds rowsum(q = m*16 + lk*4 + r) at every lm lane
#pragma unroll
    for (int m = 0; m < 2; ++m) {
        f32x4 inv;
#pragma unroll
        for (int r = 0; r < 4; ++r) inv[r] = 1.f / o_s[m][r];
#pragma unroll
        for (int dn = 0; dn < 4; ++dn)
#pragma unroll
            for (int r = 0; r < 4; ++r) {
                int row = q0 + w * 32 + m * 16 + lk * 4 + r;
                int col = h * HS + dn * 16 + lm;
                O[(size_t)(b * SQ + row) * DD + col] = (__bf16)(o[m][dn][r] * inv[r]);
            }
    }
}

extern "C" void kernel_launch(void* const* d_in, const int* in_sizes, int n_in,
                              void* d_out, int out_size, void* d_ws, size_t ws_size,
                              hipStream_t stream) {
    const float* inputs  = (const float*)d_in[0];
    const float* context = (const float*)d_in[1];
    const float* Wq = (const float*)d_in[2];
    const float* bq = (const float*)d_in[3];
    const float* Wk = (const float*)d_in[4];
    const float* bk = (const float*)d_in[5];
    const float* Wv = (const float*)d_in[6];
    const float* bv = (const float*)d_in[7];
    const float* Wo = (const float*)d_in[8];
    const float* bo = (const float*)d_in[9];
    float* out = (float*)d_out;

    char* ws = (char*)d_ws;
    const size_t SEG = (size_t)4096 * 1024 * sizeof(__bf16);  // 8 MB
    __bf16* inA  = (__bf16*)(ws + 0 * SEG);
    __bf16* ctxB = (__bf16*)(ws + 1 * SEG);
    __bf16* Wt   = (__bf16*)(ws + 2 * SEG);   // 4 x 1024x1024 bf16
    __bf16* Qb   = (__bf16*)(ws + 3 * SEG);
    __bf16* Kbuf = (__bf16*)(ws + 4 * SEG);
    __bf16* Vtb  = (__bf16*)(ws + 5 * SEG);   // V transposed + sigma-permuted by gemm_qkv
    __bf16* attb = ctxB;                      // context_bf16 dead after QKV GEMM

    int n8 = 4096 * 1024 / 8;
    cast2_f32_bf16<<<2 * n8 / 256, 256, 0, stream>>>(inputs, context, inA, ctxB, n8);
    wtrans<<<dim3(32, 32, 4), dim3(32, 8), 0, stream>>>(Wq, Wk, Wv, Wo, Wt);

    gemm_qkv<<<dim3(8, 32, 3), 256, 0, stream>>>(inA, ctxB, Wt, bq, bk, bv,
                                                 Qb, Kbuf, Vtb, SCALE * LOG2E);

    flash_attn<<<dim3(16, 32), 256, 0, stream>>>(Qb, Kbuf, Vtb, attb);

    gemm_out64<<<dim3(8, 64), 256, 0, stream>>>(attb, Wt + (size_t)3 * DD * DD, bo, out);
}

// Round 12
// 127.945 us; speedup vs baseline: 1.2500x; 1.0509x over previous
//
#include <hip/hip_runtime.h>

// Problem constants
#define BB 2
#define SQ 2048
#define SK 2048
#define DD 1024
#define HH 16
#define HS 64
#define SCALE 0.125f
#define LOG2E 1.4426950408889634f

typedef __bf16 bf16x8 __attribute__((ext_vector_type(8)));
typedef float f32x4 __attribute__((ext_vector_type(4)));
typedef unsigned int uint;

// Fast hardware exp2 (exp2f without -ffast-math lowers to the ~20-instr OCML path)
#if defined(__has_builtin)
#if __has_builtin(__builtin_amdgcn_exp2f)
#define FEXP2(x) __builtin_amdgcn_exp2f(x)
#endif
#endif
#ifndef FEXP2
extern "C" __device__ float __ocml_native_exp2_f32(float);
#define FEXP2(x) __ocml_native_exp2_f32(x)
#endif

__device__ __forceinline__ void gload_lds16(const __bf16* g, __bf16* l) {
    __builtin_amdgcn_global_load_lds((const __attribute__((address_space(1))) uint*)(g),
                                     (__attribute__((address_space(3))) uint*)(l), 16, 0, 0);
}

// ---------------- cast fp32 -> bf16 (both inputs in one launch) ----------------
__global__ void cast2_f32_bf16(const float* __restrict__ in0, const float* __restrict__ in1,
                               __bf16* __restrict__ out0, __bf16* __restrict__ out1, int n8each) {
    int i = blockIdx.x * blockDim.x + threadIdx.x;
    const float* src;
    __bf16* dst;
    int j;
    if (i < n8each) { src = in0; dst = out0; j = i; }
    else            { src = in1; dst = out1; j = i - n8each; }
    const float4* p = ((const float4*)src) + (size_t)j * 2;
    float4 a = p[0], b = p[1];
    bf16x8 v = {(__bf16)a.x, (__bf16)a.y, (__bf16)a.z, (__bf16)a.w,
                (__bf16)b.x, (__bf16)b.y, (__bf16)b.z, (__bf16)b.w};
    ((bf16x8*)dst)[j] = v;
}

// ------------- cast+transpose the 4 weight matrices [K][N] -> bf16 [N][K] -------------
__global__ void wtrans(const float* __restrict__ W0, const float* __restrict__ W1,
                       const float* __restrict__ W2, const float* __restrict__ W3,
                       __bf16* __restrict__ Wt) {
    __shared__ __bf16 tile[32][33];
    const float* W = blockIdx.z == 0 ? W0 : blockIdx.z == 1 ? W1 : blockIdx.z == 2 ? W2 : W3;
    __bf16* out = Wt + (size_t)blockIdx.z * DD * DD;
    int tx = threadIdx.x, ty = threadIdx.y;     // (32, 8)
    int k0 = blockIdx.y * 32, n0 = blockIdx.x * 32;
#pragma unroll
    for (int j = 0; j < 4; ++j)
        tile[ty + j * 8][tx] = (__bf16)W[(size_t)(k0 + ty + j * 8) * DD + n0 + tx];
    __syncthreads();
#pragma unroll
    for (int j = 0; j < 4; ++j)
        out[(size_t)(n0 + ty + j * 8) * DD + k0 + tx] = tile[tx][ty + j * 8];
}

// ------------- GEMM body: 128x64 tile, BK=64, 256 threads -------------
// 4 waves as (wr,wc) in 2x2, wave-tile 64x32, acc[4][2] = 32 AGPR so unified regs
// stay under the 128-reg occupancy step (round-11 lesson: acc[4][4] -> 160 unified
// -> 2 waves/SIMD cap). Grid 16x32x3 = 1536 blocks -> ~4 independent blocks/CU.
// MODE 0: C = bf16 (acc+bias)*scale ; MODE 2: transposed + kv-bit-permuted Vt write
#define BM 128
#define BN2 64
#define BK 64
template <int MODE>
__device__ __forceinline__ void gemm_body(__bf16 (* __restrict__ As)[BK], __bf16 (* __restrict__ Bs)[BK],
                                          const __bf16* __restrict__ A, const __bf16* __restrict__ Bt,
                                          const float* __restrict__ bias, void* __restrict__ Cout,
                                          float scale) {
    int t = threadIdx.x;
    int w = t >> 6, l = t & 63;
    int lm = l & 15, lk = l >> 4;
    int wr = w >> 1, wc = w & 1;
    int br = blockIdx.y, bc = blockIdx.x;
    int srow = (l >> 3), scol = (l & 7) * 8;
    f32x4 acc[4][2] = {};
    for (int kt = 0; kt < 1024; kt += BK) {
        __syncthreads();
#pragma unroll
        for (int j = 0; j < 4; ++j) {
            int r0 = (w * 4 + j) * 8;
            gload_lds16(&A[(size_t)(br * BM + r0 + srow) * 1024 + kt + scol], &As[r0][0]);
        }
#pragma unroll
        for (int j = 0; j < 2; ++j) {
            int r0 = (w * 2 + j) * 8;
            gload_lds16(&Bt[(size_t)(bc * BN2 + r0 + srow) * 1024 + kt + scol], &Bs[r0][0]);
        }
        __syncthreads();
#pragma unroll
        for (int kk = 0; kk < BK; kk += 32) {
            bf16x8 af[4], bf[2];
#pragma unroll
            for (int m = 0; m < 4; ++m) af[m] = *(const bf16x8*)&As[wr * 64 + m * 16 + lm][kk + lk * 8];
#pragma unroll
            for (int n = 0; n < 2; ++n) bf[n] = *(const bf16x8*)&Bs[wc * 32 + n * 16 + lm][kk + lk * 8];
#pragma unroll
            for (int m = 0; m < 4; ++m)
#pragma unroll
                for (int n = 0; n < 2; ++n)
                    acc[m][n] = __builtin_amdgcn_mfma_f32_16x16x32_bf16(af[m], bf[n], acc[m][n], 0, 0, 0);
        }
    }
#pragma unroll
    for (int m = 0; m < 4; ++m)
#pragma unroll
        for (int n = 0; n < 2; ++n) {
            int col = bc * BN2 + wc * 32 + n * 16 + lm;
            float bv = bias[col];
            if constexpr (MODE == 2) {
                // Vt value for key-pos sk stored at sigma-permuted position:
                // within 64-block: p = o5<<5 | o3<<4 | o2<<3 | o4<<2 | o1o0  (o = sk & 63)
                int row = br * BM + wr * 64 + m * 16 + lk * 4;   // sk0 (multiple of 4)
                int b_ = row >> 11, sk = row & 2047;
                int skb = sk & ~63, o = sk & 63;
                int p0 = (o & 32) | (((o >> 3) & 1) << 4) | (((o >> 2) & 1) << 3) | (((o >> 4) & 1) << 2);
                int h_ = col >> 6, d_ = col & 63;
                union { ushort4 u; __bf16 h[4]; } pk;
#pragma unroll
                for (int r = 0; r < 4; ++r) pk.h[r] = (__bf16)(acc[m][n][r] + bv);
                *(ushort4*)((__bf16*)Cout + ((size_t)((b_ * 16 + h_) * 64 + d_) * 2048 + skb + p0)) = pk.u;
            } else {
#pragma unroll
                for (int r = 0; r < 4; ++r) {
                    int row = br * BM + wr * 64 + m * 16 + lk * 4 + r;
                    ((__bf16*)Cout)[(size_t)row * 1024 + col] = (__bf16)((acc[m][n][r] + bv) * scale);
                }
            }
        }
}

// fused Q/K/V projections: z==0 -> Q (scaled), z==1 -> K, z==2 -> V written transposed+permuted as Vt
__global__ __launch_bounds__(256) void gemm_qkv(const __bf16* __restrict__ Ain, const __bf16* __restrict__ Actx,
                                                const __bf16* __restrict__ Wt,
                                                const float* __restrict__ bq, const float* __restrict__ bk,
                                                const float* __restrict__ bv,
                                                __bf16* __restrict__ Qb, __bf16* __restrict__ Kb,
                                                __bf16* __restrict__ Vtb, float qscale) {
    __shared__ __bf16 As[BM][BK];
    __shared__ __bf16 Bs[BN2][BK];
    int z = blockIdx.z;
    const __bf16* A = (z == 0) ? Ain : Actx;
    const __bf16* B = Wt + (size_t)z * DD * DD;
    if (z == 0)      gemm_body<0>(As, Bs, A, B, bq, Qb, qscale);
    else if (z == 1) gemm_body<0>(As, Bs, A, B, bk, Kb, 1.f);
    else             gemm_body<2>(As, Bs, A, B, bv, Vtb, 1.f);
}

// ------------- output GEMM: 64x128 tile (grid 512 = 2 blocks/CU), float out -------------
__global__ __launch_bounds__(256) void gemm_out64(const __bf16* __restrict__ A, const __bf16* __restrict__ Bt,
                                                  const float* __restrict__ bias, float* __restrict__ C) {
    __shared__ __bf16 As[64][64];
    __shared__ __bf16 Bs[128][64];
    int t = threadIdx.x;
    int w = t >> 6, l = t & 63;
    int lm = l & 15, lk = l >> 4;
    int br = blockIdx.y, bc = blockIdx.x;   // grid (8, 64)
    int srow = (l >> 3), scol = (l & 7) * 8;
    f32x4 acc[4][2] = {};
    for (int kt = 0; kt < 1024; kt += 64) {
        __syncthreads();
#pragma unroll
        for (int j = 0; j < 2; ++j) {
            int r0 = (j * 4 + w) * 8;
            gload_lds16(&A[(size_t)(br * 64 + r0 + srow) * 1024 + kt + scol], &As[r0][0]);
        }
#pragma unroll
        for (int j = 0; j < 4; ++j) {
            int r0 = (j * 4 + w) * 8;
            gload_lds16(&Bt[(size_t)(bc * 128 + r0 + srow) * 1024 + kt + scol], &Bs[r0][0]);
        }
        __syncthreads();
#pragma unroll
        for (int kk = 0; kk < 64; kk += 32) {
            bf16x8 af[4], bf[2];
#pragma unroll
            for (int m = 0; m < 4; ++m) af[m] = *(const bf16x8*)&As[m * 16 + lm][kk + lk * 8];
#pragma unroll
            for (int n = 0; n < 2; ++n) bf[n] = *(const bf16x8*)&Bs[w * 32 + n * 16 + lm][kk + lk * 8];
#pragma unroll
            for (int m = 0; m < 4; ++m)
#pragma unroll
                for (int n = 0; n < 2; ++n)
                    acc[m][n] = __builtin_amdgcn_mfma_f32_16x16x32_bf16(af[m], bf[n], acc[m][n], 0, 0, 0);
        }
    }
#pragma unroll
    for (int m = 0; m < 4; ++m)
#pragma unroll
        for (int n = 0; n < 2; ++n) {
            int col = bc * 128 + w * 32 + n * 16 + lm;
            float bv = bias[col];
#pragma unroll
            for (int r = 0; r < 4; ++r) {
                int row = br * 64 + m * 16 + lk * 4 + r;
                C[(size_t)row * 1024 + col] = acc[m][n][r] + bv;
            }
        }
}

// ------------- flash attention, swapped-QK^T (S^T), lane-local P -------------
// 8 waves x 16 q-rows (512 threads, QBLK=128); KVBLK=64, double-buffered K/V, 1 barrier/tile.
// Per-wave state halved vs 4-wave version -> unified regs under the 128 step -> 16 waves/CU.
// V's kv-permutation sigma baked into Vt's GLOBAL layout (gemm_qkv MODE 2).
// Hoisted addressing; advancing global pointers; ones-MFMA row-sums; HW exp2.
__global__ __launch_bounds__(512) void flash_attn(const __bf16* __restrict__ Q,
                                                  const __bf16* __restrict__ Kb,
                                                  const __bf16* __restrict__ Vt,
                                                  __bf16* __restrict__ O) {
    __shared__ __bf16 Ks[2][64 * 64];
    __shared__ __bf16 Vs[2][64 * 64];
    int t = threadIdx.x, w = t >> 6, l = t & 63;
    int lm = l & 15, lk = l >> 4;
    int bh = blockIdx.y, b = bh >> 4, h = bh & 15;
    int q0 = blockIdx.x * 128;

    // Q fragments straight from global (one-time): wave w owns q rows q0+w*16 .. +15
    bf16x8 qf[2];
#pragma unroll
    for (int kk = 0; kk < 2; ++kk)
        qf[kk] = *(const bf16x8*)&Q[(size_t)(b * SQ + q0 + w * 16 + lm) * DD + h * HS + kk * 32 + lk * 8];

    // staging geometry: 512 threads cover the 64x64 tile once: row r0 = t>>3, chunk c8 = t&7
    int r0 = t >> 3, c8 = t & 7;
    int chs = c8 ^ (r0 & 7);
    __bf16* ksl0 = &Ks[0][r0 * 64 + chs * 8];
    __bf16* vsl0 = &Vs[0][r0 * 64 + chs * 8];

    // advancing global pointers (K: +64 rows/tile; V: +64 cols/tile)
    const __bf16* kp0 = Kb + (size_t)b * SK * DD + h * HS + (size_t)r0 * DD + c8 * 8;
    const __bf16* vp0 = Vt + (size_t)bh * HS * SK + (size_t)r0 * SK + c8 * 8;

    // per-lane swizzled LDS read offsets (elements): row term lm*64 folded in
    int o0 = lm * 64 + ((lk ^ (lm & 7)) * 8);
    int o1 = lm * 64 + (((4 + lk) ^ (lm & 7)) * 8);

    float4 kr0, vr0;   // NAMED regs only (arrays -> scratch)
#define FA_LOAD()                                                                \
    kr0 = *(const float4*)kp0; vr0 = *(const float4*)vp0;                        \
    kp0 += (size_t)64 * DD; vp0 += 64;
#define FA_WRITE(BUF)                                                            \
    *(float4*)(ksl0 + (BUF) * 4096) = kr0;                                       \
    *(float4*)(vsl0 + (BUF) * 4096) = vr0;

    FA_LOAD();
    FA_WRITE(0);
    __syncthreads();

    bf16x8 ones;
#pragma unroll
    for (int j = 0; j < 8; ++j) ones[j] = (__bf16)1.0f;

    f32x4 o[4] = {};
    f32x4 o_s = {};

    for (int it = 0; it < 32; ++it) {
        int buf = it & 1;
        if (it + 1 < 32) { FA_LOAD(); }   // issue early; hides under compute

        const __bf16* KsB = &Ks[buf][0];
        const __bf16* VsB = &Vs[buf][0];

        // S^T = K Q^T : st[n], lane holds P[q=w*16+lm][kv=16n+4lk+r]
        f32x4 st[4] = {};
        __builtin_amdgcn_s_setprio(1);
#pragma unroll
        for (int kk = 0; kk < 2; ++kk) {
#pragma unroll
            for (int n = 0; n < 4; ++n) {
                bf16x8 kf = *(const bf16x8*)&KsB[(kk ? o1 : o0) + n * 1024];
                st[n] = __builtin_amdgcn_mfma_f32_16x16x32_bf16(kf, qf[kk], st[n], 0, 0, 0);
            }
        }
        __builtin_amdgcn_s_setprio(0);

        // P = exp2(S) fused into fragment assembly; PV + ones-column row-sum
#pragma unroll
        for (int kk = 0; kk < 2; ++kk) {
            bf16x8 pa;
#pragma unroll
            for (int j = 0; j < 8; ++j)
                pa[j] = (__bf16)FEXP2(st[2 * kk + (j >> 2)][j & 3]);
            __builtin_amdgcn_s_setprio(1);
            o_s = __builtin_amdgcn_mfma_f32_16x16x32_bf16(pa, ones, o_s, 0, 0, 0);
#pragma unroll
            for (int dn = 0; dn < 4; ++dn) {
                bf16x8 vf = *(const bf16x8*)&VsB[(kk ? o1 : o0) + dn * 1024];
                o[dn] = __builtin_amdgcn_mfma_f32_16x16x32_bf16(pa, vf, o[dn], 0, 0, 0);
            }
            __builtin_amdgcn_s_setprio(0);
        }

        if (it + 1 < 32) { FA_WRITE(buf ^ 1); }        // lands in the other buffer
        __syncthreads();                               // one barrier per tile
    }

    // epilogue: o_s[r] holds rowsum(q = w*16 + lk*4 + r) at every lm lane
    f32x4 inv;
#pragma unroll
    for (int r = 0; r < 4; ++r) inv[r] = 1.f / o_s[r];
#pragma unroll
    for (int dn = 0; dn < 4; ++dn)
#pragma unroll
        for (int r = 0; r < 4; ++r) {
            int row = q0 + w * 16 + lk * 4 + r;
            int col = h * HS + dn * 16 + lm;
            O[(size_t)(b * SQ + row) * DD + col] = (__bf16)(o[dn][r] * inv[r]);
        }
}

extern "C" void kernel_launch(void* const* d_in, const int* in_sizes, int n_in,
                              void* d_out, int out_size, void* d_ws, size_t ws_size,
                              hipStream_t stream) {
    const float* inputs  = (const float*)d_in[0];
    const float* context = (const float*)d_in[1];
    const float* Wq = (const float*)d_in[2];
    const float* bq = (const float*)d_in[3];
    const float* Wk = (const float*)d_in[4];
    const float* bk = (const float*)d_in[5];
    const float* Wv = (const float*)d_in[6];
    const float* bv = (const float*)d_in[7];
    const float* Wo = (const float*)d_in[8];
    const float* bo = (const float*)d_in[9];
    float* out = (float*)d_out;

    char* ws = (char*)d_ws;
    const size_t SEG = (size_t)4096 * 1024 * sizeof(__bf16);  // 8 MB
    __bf16* inA  = (__bf16*)(ws + 0 * SEG);
    __bf16* ctxB = (__bf16*)(ws + 1 * SEG);
    __bf16* Wt   = (__bf16*)(ws + 2 * SEG);   // 4 x 1024x1024 bf16
    __bf16* Qb   = (__bf16*)(ws + 3 * SEG);
    __bf16* Kbuf = (__bf16*)(ws + 4 * SEG);
    __bf16* Vtb  = (__bf16*)(ws + 5 * SEG);   // V transposed + sigma-permuted by gemm_qkv
    __bf16* attb = ctxB;                      // context_bf16 dead after QKV GEMM

    int n8 = 4096 * 1024 / 8;
    cast2_f32_bf16<<<2 * n8 / 256, 256, 0, stream>>>(inputs, context, inA, ctxB, n8);
    wtrans<<<dim3(32, 32, 4), dim3(32, 8), 0, stream>>>(Wq, Wk, Wv, Wo, Wt);

    gemm_qkv<<<dim3(16, 32, 3), 256, 0, stream>>>(inA, ctxB, Wt, bq, bk, bv,
                                                  Qb, Kbuf, Vtb, SCALE * LOG2E);

    flash_attn<<<dim3(16, 32), 512, 0, stream>>>(Qb, Kbuf, Vtb, attb);

    gemm_out64<<<dim3(8, 64), 256, 0, stream>>>(attb, Wt + (size_t)3 * DD * DD, bo, out);
}

// Round 13
// 124.784 us; speedup vs baseline: 1.2817x; 1.0253x over previous
//
#include <hip/hip_runtime.h>

// Problem constants
#define BB 2
#define SQ 2048
#define SK 2048
#define DD 1024
#define HH 16
#define HS 64
#define SCALE 0.125f
#define LOG2E 1.4426950408889634f

typedef __bf16 bf16x8 __attribute__((ext_vector_type(8)));
typedef float f32x4 __attribute__((ext_vector_type(4)));
typedef unsigned int uint;

// Fast hardware exp2 (exp2f without -ffast-math lowers to the ~20-instr OCML path)
#if defined(__has_builtin)
#if __has_builtin(__builtin_amdgcn_exp2f)
#define FEXP2(x) __builtin_amdgcn_exp2f(x)
#endif
#endif
#ifndef FEXP2
extern "C" __device__ float __ocml_native_exp2_f32(float);
#define FEXP2(x) __ocml_native_exp2_f32(x)
#endif

__device__ __forceinline__ void gload_lds16(const __bf16* g, __bf16* l) {
    __builtin_amdgcn_global_load_lds((const __attribute__((address_space(1))) uint*)(g),
                                     (__attribute__((address_space(3))) uint*)(l), 16, 0, 0);
}

// ------------- cast+transpose the 4 weight matrices [K][N] -> bf16 [N][K] -------------
__global__ void wtrans(const float* __restrict__ W0, const float* __restrict__ W1,
                       const float* __restrict__ W2, const float* __restrict__ W3,
                       __bf16* __restrict__ Wt) {
    __shared__ __bf16 tile[32][33];
    const float* W = blockIdx.z == 0 ? W0 : blockIdx.z == 1 ? W1 : blockIdx.z == 2 ? W2 : W3;
    __bf16* out = Wt + (size_t)blockIdx.z * DD * DD;
    int tx = threadIdx.x, ty = threadIdx.y;     // (32, 8)
    int k0 = blockIdx.y * 32, n0 = blockIdx.x * 32;
#pragma unroll
    for (int j = 0; j < 4; ++j)
        tile[ty + j * 8][tx] = (__bf16)W[(size_t)(k0 + ty + j * 8) * DD + n0 + tx];
    __syncthreads();
#pragma unroll
    for (int j = 0; j < 4; ++j)
        out[(size_t)(n0 + ty + j * 8) * DD + k0 + tx] = tile[tx][ty + j * 8];
}

// ------------- GEMM body: 128x64 tile, BK=64, 256 threads -------------
// A read DIRECTLY as fp32 (fused cast): T14 reg-staged (named float4 regs, loads for
// step t+1 issued under step t's MFMAs), converted to bf16 at ds_write, XOR-chunk
// swizzled LDS (flash-proven pattern, conflict-free). B staged via global_load_lds.
// acc[4][2] = 32 AGPR keeps unified regs under the 128 occupancy step.
// T1 XCD swizzle: 512 wgs per z-slice -> each XCD owns 4 contiguous row-panels.
// MODE 0: C = bf16 (acc+bias)*scale ; MODE 2: transposed + kv-bit-permuted Vt write
#define BM 128
#define BN2 64
#define BK 64
template <int MODE>
__device__ __forceinline__ void gemm_body(__bf16 (* __restrict__ As)[BK], __bf16 (* __restrict__ Bs)[BK],
                                          const float* __restrict__ Af, const __bf16* __restrict__ Bt,
                                          const float* __restrict__ bias, void* __restrict__ Cout,
                                          float scale) {
    int t = threadIdx.x;
    int w = t >> 6, l = t & 63;
    int lm = l & 15, lk = l >> 4;
    int wr = w >> 1, wc = w & 1;
    // T1: flat id over (bc,br); 512 wgs, 8 XCDs -> XCD gets 64 contiguous (4 br x 16 bc)
    int flat = blockIdx.x + 16 * blockIdx.y;
    int nf = (flat & 7) * 64 + (flat >> 3);
    int bc = nf & 15, br = nf >> 4;
    int srow = l >> 3, sc8 = l & 7;

    // A fp32 per-thread base: row = br*BM + w*32 + j*8 + srow, col chunk sc8*8 (+kt)
    const float* ag = Af + (size_t)(br * BM + w * 32 + srow) * 1024 + sc8 * 8;
    // As write base, swizzled chunk (row&7 == srow)
    __bf16* aw = &As[w * 32 + srow][(sc8 ^ srow) * 8];

    float4 xa0, xa1, xb0, xb1, xc0, xc1, xd0, xd1;   // NAMED regs only
#define GA_LOAD(KT)                                                                   \
    xa0 = *(const float4*)(ag + (KT));          xa1 = *(const float4*)(ag + (KT) + 4);\
    xb0 = *(const float4*)(ag + 8192 + (KT));   xb1 = *(const float4*)(ag + 8192 + (KT) + 4);\
    xc0 = *(const float4*)(ag + 16384 + (KT));  xc1 = *(const float4*)(ag + 16384 + (KT) + 4);\
    xd0 = *(const float4*)(ag + 24576 + (KT));  xd1 = *(const float4*)(ag + 24576 + (KT) + 4);
#define GA_WRITE()                                                                    \
    {                                                                                 \
        bf16x8 va = {(__bf16)xa0.x, (__bf16)xa0.y, (__bf16)xa0.z, (__bf16)xa0.w,      \
                     (__bf16)xa1.x, (__bf16)xa1.y, (__bf16)xa1.z, (__bf16)xa1.w};     \
        bf16x8 vb = {(__bf16)xb0.x, (__bf16)xb0.y, (__bf16)xb0.z, (__bf16)xb0.w,      \
                     (__bf16)xb1.x, (__bf16)xb1.y, (__bf16)xb1.z, (__bf16)xb1.w};     \
        bf16x8 vc = {(__bf16)xc0.x, (__bf16)xc0.y, (__bf16)xc0.z, (__bf16)xc0.w,      \
                     (__bf16)xc1.x, (__bf16)xc1.y, (__bf16)xc1.z, (__bf16)xc1.w};     \
        bf16x8 vd = {(__bf16)xd0.x, (__bf16)xd0.y, (__bf16)xd0.z, (__bf16)xd0.w,      \
                     (__bf16)xd1.x, (__bf16)xd1.y, (__bf16)xd1.z, (__bf16)xd1.w};     \
        *(bf16x8*)(aw)        = va;                                                   \
        *(bf16x8*)(aw + 512)  = vb;                                                   \
        *(bf16x8*)(aw + 1024) = vc;                                                   \
        *(bf16x8*)(aw + 1536) = vd;                                                   \
    }

    f32x4 acc[4][2] = {};
    GA_LOAD(0);
    for (int kt = 0; kt < 1024; kt += BK) {
        __syncthreads();                       // previous step's LDS reads done
        GA_WRITE();                            // land A tile (cvt fp32->bf16 here)
#pragma unroll
        for (int j = 0; j < 2; ++j) {
            int r0 = (w * 2 + j) * 8;
            gload_lds16(&Bt[(size_t)(bc * BN2 + r0 + srow) * 1024 + kt + sc8 * 8], &Bs[r0][0]);
        }
        __syncthreads();                       // drains ds_write + gload_lds
        if (kt + BK < 1024) { GA_LOAD(kt + BK); }   // next tile's loads hide under MFMA
#pragma unroll
        for (int kk = 0; kk < BK; kk += 32) {
            bf16x8 af[4], bf[2];
#pragma unroll
            for (int m = 0; m < 4; ++m)
                af[m] = *(const bf16x8*)&As[wr * 64 + m * 16 + lm][((((kk >> 3) + lk)) ^ (lm & 7)) * 8];
#pragma unroll
            for (int n = 0; n < 2; ++n) bf[n] = *(const bf16x8*)&Bs[wc * 32 + n * 16 + lm][kk + lk * 8];
#pragma unroll
            for (int m = 0; m < 4; ++m)
#pragma unroll
                for (int n = 0; n < 2; ++n)
                    acc[m][n] = __builtin_amdgcn_mfma_f32_16x16x32_bf16(af[m], bf[n], acc[m][n], 0, 0, 0);
        }
    }
#pragma unroll
    for (int m = 0; m < 4; ++m)
#pragma unroll
        for (int n = 0; n < 2; ++n) {
            int col = bc * BN2 + wc * 32 + n * 16 + lm;
            float bv = bias[col];
            if constexpr (MODE == 2) {
                // Vt value for key-pos sk stored at sigma-permuted position:
                // within 64-block: p = o5<<5 | o3<<4 | o2<<3 | o4<<2 | o1o0  (o = sk & 63)
                int row = br * BM + wr * 64 + m * 16 + lk * 4;   // sk0 (multiple of 4)
                int b_ = row >> 11, sk = row & 2047;
                int skb = sk & ~63, o = sk & 63;
                int p0 = (o & 32) | (((o >> 3) & 1) << 4) | (((o >> 2) & 1) << 3) | (((o >> 4) & 1) << 2);
                int h_ = col >> 6, d_ = col & 63;
                union { ushort4 u; __bf16 h[4]; } pk;
#pragma unroll
                for (int r = 0; r < 4; ++r) pk.h[r] = (__bf16)(acc[m][n][r] + bv);
                *(ushort4*)((__bf16*)Cout + ((size_t)((b_ * 16 + h_) * 64 + d_) * 2048 + skb + p0)) = pk.u;
            } else {
#pragma unroll
                for (int r = 0; r < 4; ++r) {
                    int row = br * BM + wr * 64 + m * 16 + lk * 4 + r;
                    ((__bf16*)Cout)[(size_t)row * 1024 + col] = (__bf16)((acc[m][n][r] + bv) * scale);
                }
            }
        }
#undef GA_LOAD
#undef GA_WRITE
}

// fused Q/K/V projections (A read directly as fp32 -- cast kernel eliminated):
// z==0 -> Q (scaled), z==1 -> K, z==2 -> V written transposed+permuted as Vt
__global__ __launch_bounds__(256) void gemm_qkv(const float* __restrict__ Ain, const float* __restrict__ Actx,
                                                const __bf16* __restrict__ Wt,
                                                const float* __restrict__ bq, const float* __restrict__ bk,
                                                const float* __restrict__ bv,
                                                __bf16* __restrict__ Qb, __bf16* __restrict__ Kb,
                                                __bf16* __restrict__ Vtb, float qscale) {
    __shared__ __bf16 As[BM][BK];
    __shared__ __bf16 Bs[BN2][BK];
    int z = blockIdx.z;
    const float* A = (z == 0) ? Ain : Actx;
    const __bf16* B = Wt + (size_t)z * DD * DD;
    if (z == 0)      gemm_body<0>(As, Bs, A, B, bq, Qb, qscale);
    else if (z == 1) gemm_body<0>(As, Bs, A, B, bk, Kb, 1.f);
    else             gemm_body<2>(As, Bs, A, B, bv, Vtb, 1.f);
}

// ------------- output GEMM: 64x128 tile, float out, T1 XCD swizzle -------------
__global__ __launch_bounds__(256) void gemm_out64(const __bf16* __restrict__ A, const __bf16* __restrict__ Bt,
                                                  const float* __restrict__ bias, float* __restrict__ C) {
    __shared__ __bf16 As[64][64];
    __shared__ __bf16 Bs[128][64];
    int t = threadIdx.x;
    int w = t >> 6, l = t & 63;
    int lm = l & 15, lk = l >> 4;
    // T1: grid (8,64) = 512 wgs -> XCD gets 8 br x 8 bc
    int flat = blockIdx.x + 8 * blockIdx.y;
    int nf = (flat & 7) * 64 + (flat >> 3);
    int bc = nf & 7, br = nf >> 3;
    int srow = (l >> 3), scol = (l & 7) * 8;
    f32x4 acc[4][2] = {};
    for (int kt = 0; kt < 1024; kt += 64) {
        __syncthreads();
#pragma unroll
        for (int j = 0; j < 2; ++j) {
            int r0 = (j * 4 + w) * 8;
            gload_lds16(&A[(size_t)(br * 64 + r0 + srow) * 1024 + kt + scol], &As[r0][0]);
        }
#pragma unroll
        for (int j = 0; j < 4; ++j) {
            int r0 = (j * 4 + w) * 8;
            gload_lds16(&Bt[(size_t)(bc * 128 + r0 + srow) * 1024 + kt + scol], &Bs[r0][0]);
        }
        __syncthreads();
#pragma unroll
        for (int kk = 0; kk < 64; kk += 32) {
            bf16x8 af[4], bf[2];
#pragma unroll
            for (int m = 0; m < 4; ++m) af[m] = *(const bf16x8*)&As[m * 16 + lm][kk + lk * 8];
#pragma unroll
            for (int n = 0; n < 2; ++n) bf[n] = *(const bf16x8*)&Bs[w * 32 + n * 16 + lm][kk + lk * 8];
#pragma unroll
            for (int m = 0; m < 4; ++m)
#pragma unroll
                for (int n = 0; n < 2; ++n)
                    acc[m][n] = __builtin_amdgcn_mfma_f32_16x16x32_bf16(af[m], bf[n], acc[m][n], 0, 0, 0);
        }
    }
#pragma unroll
    for (int m = 0; m < 4; ++m)
#pragma unroll
        for (int n = 0; n < 2; ++n) {
            int col = bc * 128 + w * 32 + n * 16 + lm;
            float bv = bias[col];
#pragma unroll
            for (int r = 0; r < 4; ++r) {
                int row = br * 64 + m * 16 + lk * 4 + r;
                C[(size_t)row * 1024 + col] = acc[m][n][r] + bv;
            }
        }
}

// ------------- flash attention, swapped-QK^T (S^T), lane-local P -------------
// 8 waves x 16 q-rows (512 threads, QBLK=128); KVBLK=64, double-buffered K/V, 1 barrier/tile.
// V's kv-permutation sigma baked into Vt's GLOBAL layout (gemm_qkv MODE 2).
// Hoisted addressing; advancing global pointers; ones-MFMA row-sums; HW exp2; T1 swizzle.
__global__ __launch_bounds__(512) void flash_attn(const __bf16* __restrict__ Q,
                                                  const __bf16* __restrict__ Kb,
                                                  const __bf16* __restrict__ Vt,
                                                  __bf16* __restrict__ O) {
    __shared__ __bf16 Ks[2][64 * 64];
    __shared__ __bf16 Vs[2][64 * 64];
    int t = threadIdx.x, w = t >> 6, l = t & 63;
    int lm = l & 15, lk = l >> 4;
    // T1: grid (16,32) = 512 wgs -> XCD gets 4 bh x 16 q-tiles (KV panels L2-resident)
    int flat = blockIdx.x + 16 * blockIdx.y;
    int nf = (flat & 7) * 64 + (flat >> 3);
    int bh = nf >> 4, b = bh >> 4, h = bh & 15;
    int q0 = (nf & 15) * 128;

    // Q fragments straight from global (one-time): wave w owns q rows q0+w*16 .. +15
    bf16x8 qf[2];
#pragma unroll
    for (int kk = 0; kk < 2; ++kk)
        qf[kk] = *(const bf16x8*)&Q[(size_t)(b * SQ + q0 + w * 16 + lm) * DD + h * HS + kk * 32 + lk * 8];

    // staging geometry: 512 threads cover the 64x64 tile once: row r0 = t>>3, chunk c8 = t&7
    int r0 = t >> 3, c8 = t & 7;
    int chs = c8 ^ (r0 & 7);
    __bf16* ksl0 = &Ks[0][r0 * 64 + chs * 8];
    __bf16* vsl0 = &Vs[0][r0 * 64 + chs * 8];

    // advancing global pointers (K: +64 rows/tile; V: +64 cols/tile)
    const __bf16* kp0 = Kb + (size_t)b * SK * DD + h * HS + (size_t)r0 * DD + c8 * 8;
    const __bf16* vp0 = Vt + (size_t)bh * HS * SK + (size_t)r0 * SK + c8 * 8;

    // per-lane swizzled LDS read offsets (elements): row term lm*64 folded in
    int o0 = lm * 64 + ((lk ^ (lm & 7)) * 8);
    int o1 = lm * 64 + (((4 + lk) ^ (lm & 7)) * 8);

    float4 kr0, vr0;   // NAMED regs only (arrays -> scratch)
#define FA_LOAD()                                                                \
    kr0 = *(const float4*)kp0; vr0 = *(const float4*)vp0;                        \
    kp0 += (size_t)64 * DD; vp0 += 64;
#define FA_WRITE(BUF)                                                            \
    *(float4*)(ksl0 + (BUF) * 4096) = kr0;                                       \
    *(float4*)(vsl0 + (BUF) * 4096) = vr0;

    FA_LOAD();
    FA_WRITE(0);
    __syncthreads();

    bf16x8 ones;
#pragma unroll
    for (int j = 0; j < 8; ++j) ones[j] = (__bf16)1.0f;

    f32x4 o[4] = {};
    f32x4 o_s = {};

    for (int it = 0; it < 32; ++it) {
        int buf = it & 1;
        if (it + 1 < 32) { FA_LOAD(); }   // issue early; hides under compute

        const __bf16* KsB = &Ks[buf][0];
        const __bf16* VsB = &Vs[buf][0];

        // S^T = K Q^T : st[n], lane holds P[q=w*16+lm][kv=16n+4lk+r]
        f32x4 st[4] = {};
        __builtin_amdgcn_s_setprio(1);
#pragma unroll
        for (int kk = 0; kk < 2; ++kk) {
#pragma unroll
            for (int n = 0; n < 4; ++n) {
                bf16x8 kf = *(const bf16x8*)&KsB[(kk ? o1 : o0) + n * 1024];
                st[n] = __builtin_amdgcn_mfma_f32_16x16x32_bf16(kf, qf[kk], st[n], 0, 0, 0);
            }
        }
        __builtin_amdgcn_s_setprio(0);

        // P = exp2(S) fused into fragment assembly; PV + ones-column row-sum
#pragma unroll
        for (int kk = 0; kk < 2; ++kk) {
            bf16x8 pa;
#pragma unroll
            for (int j = 0; j < 8; ++j)
                pa[j] = (__bf16)FEXP2(st[2 * kk + (j >> 2)][j & 3]);
            __builtin_amdgcn_s_setprio(1);
            o_s = __builtin_amdgcn_mfma_f32_16x16x32_bf16(pa, ones, o_s, 0, 0, 0);
#pragma unroll
            for (int dn = 0; dn < 4; ++dn) {
                bf16x8 vf = *(const bf16x8*)&VsB[(kk ? o1 : o0) + dn * 1024];
                o[dn] = __builtin_amdgcn_mfma_f32_16x16x32_bf16(pa, vf, o[dn], 0, 0, 0);
            }
            __builtin_amdgcn_s_setprio(0);
        }

        if (it + 1 < 32) { FA_WRITE(buf ^ 1); }        // lands in the other buffer
        __syncthreads();                               // one barrier per tile
    }

    // epilogue: o_s[r] holds rowsum(q = w*16 + lk*4 + r) at every lm lane
    f32x4 inv;
#pragma unroll
    for (int r = 0; r < 4; ++r) inv[r] = 1.f / o_s[r];
#pragma unroll
    for (int dn = 0; dn < 4; ++dn)
#pragma unroll
        for (int r = 0; r < 4; ++r) {
            int row = q0 + w * 16 + lk * 4 + r;
            int col = h * HS + dn * 16 + lm;
            O[(size_t)(b * SQ + row) * DD + col] = (__bf16)(o[dn][r] * inv[r]);
        }
}

extern "C" void kernel_launch(void* const* d_in, const int* in_sizes, int n_in,
                              void* d_out, int out_size, void* d_ws, size_t ws_size,
                              hipStream_t stream) {
    const float* inputs  = (const float*)d_in[0];
    const float* context = (const float*)d_in[1];
    const float* Wq = (const float*)d_in[2];
    const float* bq = (const float*)d_in[3];
    const float* Wk = (const float*)d_in[4];
    const float* bk = (const float*)d_in[5];
    const float* Wv = (const float*)d_in[6];
    const float* bv = (const float*)d_in[7];
    const float* Wo = (const float*)d_in[8];
    const float* bo = (const float*)d_in[9];
    float* out = (float*)d_out;

    char* ws = (char*)d_ws;
    const size_t SEG = (size_t)4096 * 1024 * sizeof(__bf16);  // 8 MB
    __bf16* attb = (__bf16*)(ws + 0 * SEG);   // attention output (bf16)
    __bf16* Wt   = (__bf16*)(ws + 2 * SEG);   // 4 x 1024x1024 bf16
    __bf16* Qb   = (__bf16*)(ws + 3 * SEG);
    __bf16* Kbuf = (__bf16*)(ws + 4 * SEG);
    __bf16* Vtb  = (__bf16*)(ws + 5 * SEG);   // V transposed + sigma-permuted by gemm_qkv

    wtrans<<<dim3(32, 32, 4), dim3(32, 8), 0, stream>>>(Wq, Wk, Wv, Wo, Wt);

    gemm_qkv<<<dim3(16, 32, 3), 256, 0, stream>>>(inputs, context, Wt, bq, bk, bv,
                                                  Qb, Kbuf, Vtb, SCALE * LOG2E);

    flash_attn<<<dim3(16, 32), 512, 0, stream>>>(Qb, Kbuf, Vtb, attb);

    gemm_out64<<<dim3(8, 64), 256, 0, stream>>>(attb, Wt + (size_t)3 * DD * DD, bo, out);
}

// Round 14
// 113.822 us; speedup vs baseline: 1.4051x; 1.0963x over previous
//
#include <hip/hip_runtime.h>

// Problem constants
#define BB 2
#define SQ 2048
#define SK 2048
#define DD 1024
#define HH 16
#define HS 64
#define SCALE 0.125f
#define LOG2E 1.4426950408889634f

typedef __bf16 bf16x8 __attribute__((ext_vector_type(8)));
typedef float f32x4 __attribute__((ext_vector_type(4)));
typedef unsigned int uint;

// Fast hardware exp2 (exp2f without -ffast-math lowers to the ~20-instr OCML path)
#if defined(__has_builtin)
#if __has_builtin(__builtin_amdgcn_exp2f)
#define FEXP2(x) __builtin_amdgcn_exp2f(x)
#endif
#endif
#ifndef FEXP2
extern "C" __device__ float __ocml_native_exp2_f32(float);
#define FEXP2(x) __ocml_native_exp2_f32(x)
#endif

__device__ __forceinline__ void gload_lds16(const __bf16* g, __bf16* l) {
    __builtin_amdgcn_global_load_lds((const __attribute__((address_space(1))) uint*)(g),
                                     (__attribute__((address_space(3))) uint*)(l), 16, 0, 0);
}

// ------------- cast+transpose weights [K][N] -> bf16 [N][K], B-read swizzle baked in -------------
// element (n, k) stored at column (k & ~63) | (((k>>3) ^ n) & 7)<<3 | (k&7): after linear
// gload_lds staging, GEMM B-reads at chunk ((kk>>3)+lk)^(row&7) are conflict-free.
__global__ void wtrans(const float* __restrict__ W0, const float* __restrict__ W1,
                       const float* __restrict__ W2, const float* __restrict__ W3,
                       __bf16* __restrict__ Wt) {
    __shared__ __bf16 tile[32][33];
    const float* W = blockIdx.z == 0 ? W0 : blockIdx.z == 1 ? W1 : blockIdx.z == 2 ? W2 : W3;
    __bf16* out = Wt + (size_t)blockIdx.z * DD * DD;
    int tx = threadIdx.x, ty = threadIdx.y;     // (32, 8)
    int k0 = blockIdx.y * 32, n0 = blockIdx.x * 32;
#pragma unroll
    for (int j = 0; j < 4; ++j)
        tile[ty + j * 8][tx] = (__bf16)W[(size_t)(k0 + ty + j * 8) * DD + n0 + tx];
    __syncthreads();
#pragma unroll
    for (int j = 0; j < 4; ++j) {
        int n = n0 + ty + j * 8;
        int k = k0 + tx;
        int kswz = (k & ~63) | ((((k >> 3) ^ n) & 7) << 3) | (k & 7);
        out[(size_t)n * DD + kswz] = tile[tx][ty + j * 8];
    }
}

// ------------- unified QKV projection GEMM -------------
// Every block: A-tile 64 rows x 64 fp32 (reg-staged fused cast, XOR-chunk swizzled LDS),
// B-tile 128 rows x 64 bf16 (reg-staged from pre-swizzled Wt -> linear LDS write, swizzled read).
// Q-blocks (nf<512): A=inputs, B = 128 cols of Wq.  KV-blocks: A=context, B = 64 cols Wk + 64 cols Wv
// (one A staging feeds BOTH outputs -> 2x intensity). Identical inner loop: acc[2][4], 16 MFMA/wave/kt.
// T14: loads for kt+1 issued after barrier-2, under MFMA -> no vmcnt drain in the loop.
// acc 32 + stage 32 + addr ~40 regs, __launch_bounds__(256,4) caps at 128 -> 4 blocks/CU (24KB LDS).
__global__ __launch_bounds__(256, 4) void gemm_qkv(
        const float* __restrict__ Ain, const float* __restrict__ Actx,
        const __bf16* __restrict__ Wt,
        const float* __restrict__ bq, const float* __restrict__ bk, const float* __restrict__ bv,
        __bf16* __restrict__ Qb, __bf16* __restrict__ Kb, __bf16* __restrict__ Vtb,
        float qscale) {
    __shared__ __bf16 As[64][64];     // 8 KB
    __shared__ __bf16 Bs[128][64];    // 16 KB
    int t = threadIdx.x, w = t >> 6, l = t & 63;
    int lm = l & 15, lk = l >> 4;
    int wr = w >> 1, wc = w & 1;
    // T1 XCD swizzle over 1536 wgs (grid 16x96): each XCD gets 192 contiguous nf
    int flat = blockIdx.x + 16 * blockIdx.y;
    int nf = (flat & 7) * 192 + (flat >> 3);
    bool isQ = nf < 512;
    int bc, br;
    if (isQ) { bc = nf & 7; br = nf >> 3; }                    // 8 col-tiles(128) x 64 row-tiles
    else     { int f = nf - 512; bc = f & 15; br = f >> 4; }   // 16 col-tiles(64) x 64 row-tiles

    // A staging geometry: row ra = t>>2, fp32 cols ca*8 .. ca*8+15 (two bf16x8 chunks)
    int ra = t >> 2, ca = (t & 3) * 2;
    const float* ag = (isQ ? Ain : Actx) + (size_t)(br * 64 + ra) * 1024 + ca * 8;
    __bf16* aw0 = &As[ra][((ca)     ^ (ra & 7)) * 8];
    __bf16* aw1 = &As[ra][((ca + 1) ^ (ra & 7)) * 8];

    // B staging geometry: rows rb, rb+32, rb+64, rb+96; chunk c8 (source pre-swizzled)
    int rb = t >> 3, c8 = t & 7;
    const __bf16 *bg0, *bg1, *bg2, *bg3;
    if (isQ) {
        const __bf16* Wq_ = Wt;
        bg0 = Wq_ + (size_t)(bc * 128 + rb)      * 1024 + c8 * 8;
        bg1 = Wq_ + (size_t)(bc * 128 + rb + 32) * 1024 + c8 * 8;
        bg2 = Wq_ + (size_t)(bc * 128 + rb + 64) * 1024 + c8 * 8;
        bg3 = Wq_ + (size_t)(bc * 128 + rb + 96) * 1024 + c8 * 8;
    } else {
        const __bf16* Wk_ = Wt + (size_t)DD * DD;
        const __bf16* Wv_ = Wt + (size_t)2 * DD * DD;
        bg0 = Wk_ + (size_t)(bc * 64 + rb)      * 1024 + c8 * 8;
        bg1 = Wk_ + (size_t)(bc * 64 + rb + 32) * 1024 + c8 * 8;
        bg2 = Wv_ + (size_t)(bc * 64 + rb)      * 1024 + c8 * 8;
        bg3 = Wv_ + (size_t)(bc * 64 + rb + 32) * 1024 + c8 * 8;
    }
    __bf16* bw0 = &Bs[rb][c8 * 8];
    __bf16* bw1 = &Bs[rb + 32][c8 * 8];
    __bf16* bw2 = &Bs[rb + 64][c8 * 8];
    __bf16* bw3 = &Bs[rb + 96][c8 * 8];

    // B fragment row indices (row&7 == lm&7 for all -> swizzled-chunk reads conflict-free)
    int brow[4];
#pragma unroll
    for (int n = 0; n < 4; ++n)
        brow[n] = isQ ? (wc * 64 + n * 16 + lm)
                      : ((n >> 1) * 64 + wc * 32 + (n & 1) * 16 + lm);

    float4 xa0, xa1, xa2, xa3, xb0, xb1, xb2, xb3;   // NAMED regs only
#define G_LOAD()                                                                      \
    xa0 = *(const float4*)(ag);     xa1 = *(const float4*)(ag + 4);                   \
    xa2 = *(const float4*)(ag + 8); xa3 = *(const float4*)(ag + 12);                  \
    xb0 = *(const float4*)bg0; xb1 = *(const float4*)bg1;                             \
    xb2 = *(const float4*)bg2; xb3 = *(const float4*)bg3;                             \
    ag += 64; bg0 += 64; bg1 += 64; bg2 += 64; bg3 += 64;
#define G_WRITE()                                                                     \
    {                                                                                 \
        bf16x8 va0 = {(__bf16)xa0.x, (__bf16)xa0.y, (__bf16)xa0.z, (__bf16)xa0.w,     \
                      (__bf16)xa1.x, (__bf16)xa1.y, (__bf16)xa1.z, (__bf16)xa1.w};    \
        bf16x8 va1 = {(__bf16)xa2.x, (__bf16)xa2.y, (__bf16)xa2.z, (__bf16)xa2.w,     \
                      (__bf16)xa3.x, (__bf16)xa3.y, (__bf16)xa3.z, (__bf16)xa3.w};    \
        *(bf16x8*)aw0 = va0; *(bf16x8*)aw1 = va1;                                     \
        *(float4*)bw0 = xb0; *(float4*)bw1 = xb1;                                     \
        *(float4*)bw2 = xb2; *(float4*)bw3 = xb3;                                     \
    }

    f32x4 acc[2][4] = {};
    G_LOAD();
    for (int kt = 0; kt < 1024; kt += 64) {
        __syncthreads();                       // previous step's LDS reads done
        G_WRITE();                             // land tiles (fp32->bf16 cvt for A)
        __syncthreads();                       // lgkm drain only (no outstanding vmem)
        if (kt + 64 < 1024) { G_LOAD(); }      // next tile's loads hide under MFMA
#pragma unroll
        for (int kk = 0; kk < 64; kk += 32) {
            int ch = ((kk >> 3) + lk);
            bf16x8 af[2], bf[4];
#pragma unroll
            for (int m = 0; m < 2; ++m)
                af[m] = *(const bf16x8*)&As[wr * 32 + m * 16 + lm][(ch ^ (lm & 7)) * 8];
#pragma unroll
            for (int n = 0; n < 4; ++n)
                bf[n] = *(const bf16x8*)&Bs[brow[n]][(ch ^ (lm & 7)) * 8];
#pragma unroll
            for (int m = 0; m < 2; ++m)
#pragma unroll
                for (int n = 0; n < 4; ++n)
                    acc[m][n] = __builtin_amdgcn_mfma_f32_16x16x32_bf16(af[m], bf[n], acc[m][n], 0, 0, 0);
        }
    }
#undef G_LOAD
#undef G_WRITE

    if (isQ) {
#pragma unroll
        for (int m = 0; m < 2; ++m)
#pragma unroll
            for (int n = 0; n < 4; ++n) {
                int col = bc * 128 + wc * 64 + n * 16 + lm;
                float bb = bq[col];
#pragma unroll
                for (int r = 0; r < 4; ++r) {
                    int row = br * 64 + wr * 32 + m * 16 + lk * 4 + r;
                    Qb[(size_t)row * 1024 + col] = (__bf16)((acc[m][n][r] + bb) * qscale);
                }
            }
    } else {
#pragma unroll
        for (int m = 0; m < 2; ++m)
#pragma unroll
            for (int n = 0; n < 4; ++n) {
                int col = bc * 64 + wc * 32 + (n & 1) * 16 + lm;
                if (n < 2) {
                    float bb = bk[col];
#pragma unroll
                    for (int r = 0; r < 4; ++r) {
                        int row = br * 64 + wr * 32 + m * 16 + lk * 4 + r;
                        Kb[(size_t)row * 1024 + col] = (__bf16)(acc[m][n][r] + bb);
                    }
                } else {
                    // Vt value for key-pos sk stored at sigma-permuted position:
                    // within 64-block: p = o5<<5 | o3<<4 | o2<<3 | o4<<2 | o1o0 (o1o0 = 0 for quad base)
                    float bb = bv[col];
                    int row = br * 64 + wr * 32 + m * 16 + lk * 4;   // sk quad base
                    int b_ = row >> 11, sk = row & 2047;
                    int skb = sk & ~63, o = sk & 63;
                    int p0 = (o & 32) | (((o >> 3) & 1) << 4) | (((o >> 2) & 1) << 3) | (((o >> 4) & 1) << 2);
                    int h_ = col >> 6, d_ = col & 63;
                    union { ushort4 u; __bf16 hh[4]; } pk;
#pragma unroll
                    for (int r = 0; r < 4; ++r) pk.hh[r] = (__bf16)(acc[m][n][r] + bb);
                    *(ushort4*)(Vtb + ((size_t)((b_ * 16 + h_) * 64 + d_) * 2048 + skb + p0)) = pk.u;
                }
            }
    }
}

// ------------- output GEMM: 64x128 tile, float out, T1 XCD swizzle -------------
// B (Wo) is pre-swizzled in global -> B reads use swizzled chunk; A (attb) linear.
__global__ __launch_bounds__(256) void gemm_out64(const __bf16* __restrict__ A, const __bf16* __restrict__ Bt,
                                                  const float* __restrict__ bias, float* __restrict__ C) {
    __shared__ __bf16 As[64][64];
    __shared__ __bf16 Bs[128][64];
    int t = threadIdx.x;
    int w = t >> 6, l = t & 63;
    int lm = l & 15, lk = l >> 4;
    // T1: grid (8,64) = 512 wgs -> XCD gets 8 br x 8 bc
    int flat = blockIdx.x + 8 * blockIdx.y;
    int nf = (flat & 7) * 64 + (flat >> 3);
    int bc = nf & 7, br = nf >> 3;
    int srow = (l >> 3), scol = (l & 7) * 8;
    f32x4 acc[4][2] = {};
    for (int kt = 0; kt < 1024; kt += 64) {
        __syncthreads();
#pragma unroll
        for (int j = 0; j < 2; ++j) {
            int r0 = (j * 4 + w) * 8;
            gload_lds16(&A[(size_t)(br * 64 + r0 + srow) * 1024 + kt + scol], &As[r0][0]);
        }
#pragma unroll
        for (int j = 0; j < 4; ++j) {
            int r0 = (j * 4 + w) * 8;
            gload_lds16(&Bt[(size_t)(bc * 128 + r0 + srow) * 1024 + kt + scol], &Bs[r0][0]);
        }
        __syncthreads();
#pragma unroll
        for (int kk = 0; kk < 64; kk += 32) {
            int ch = ((kk >> 3) + lk);
            bf16x8 af[4], bf[2];
#pragma unroll
            for (int m = 0; m < 4; ++m) af[m] = *(const bf16x8*)&As[m * 16 + lm][kk + lk * 8];
#pragma unroll
            for (int n = 0; n < 2; ++n)
                bf[n] = *(const bf16x8*)&Bs[w * 32 + n * 16 + lm][(ch ^ (lm & 7)) * 8];
#pragma unroll
            for (int m = 0; m < 4; ++m)
#pragma unroll
                for (int n = 0; n < 2; ++n)
                    acc[m][n] = __builtin_amdgcn_mfma_f32_16x16x32_bf16(af[m], bf[n], acc[m][n], 0, 0, 0);
        }
    }
#pragma unroll
    for (int m = 0; m < 4; ++m)
#pragma unroll
        for (int n = 0; n < 2; ++n) {
            int col = bc * 128 + w * 32 + n * 16 + lm;
            float bv = bias[col];
#pragma unroll
            for (int r = 0; r < 4; ++r) {
                int row = br * 64 + m * 16 + lk * 4 + r;
                C[(size_t)row * 1024 + col] = acc[m][n][r] + bv;
            }
        }
}

// ------------- flash attention, swapped-QK^T (S^T), lane-local P -------------
// 8 waves x 16 q-rows (512 threads, QBLK=128); KVBLK=64, double-buffered K/V, 1 barrier/tile.
// V's kv-permutation sigma baked into Vt's GLOBAL layout (gemm_qkv).
// Hoisted addressing; advancing global pointers; ones-MFMA row-sums; HW exp2; T1 swizzle.
__global__ __launch_bounds__(512) void flash_attn(const __bf16* __restrict__ Q,
                                                  const __bf16* __restrict__ Kb,
                                                  const __bf16* __restrict__ Vt,
                                                  __bf16* __restrict__ O) {
    __shared__ __bf16 Ks[2][64 * 64];
    __shared__ __bf16 Vs[2][64 * 64];
    int t = threadIdx.x, w = t >> 6, l = t & 63;
    int lm = l & 15, lk = l >> 4;
    // T1: grid (16,32) = 512 wgs -> XCD gets 4 bh x 16 q-tiles (KV panels L2-resident)
    int flat = blockIdx.x + 16 * blockIdx.y;
    int nf = (flat & 7) * 64 + (flat >> 3);
    int bh = nf >> 4, b = bh >> 4, h = bh & 15;
    int q0 = (nf & 15) * 128;

    // Q fragments straight from global (one-time): wave w owns q rows q0+w*16 .. +15
    bf16x8 qf[2];
#pragma unroll
    for (int kk = 0; kk < 2; ++kk)
        qf[kk] = *(const bf16x8*)&Q[(size_t)(b * SQ + q0 + w * 16 + lm) * DD + h * HS + kk * 32 + lk * 8];

    // staging geometry: 512 threads cover the 64x64 tile once: row r0 = t>>3, chunk c8 = t&7
    int r0 = t >> 3, c8 = t & 7;
    int chs = c8 ^ (r0 & 7);
    __bf16* ksl0 = &Ks[0][r0 * 64 + chs * 8];
    __bf16* vsl0 = &Vs[0][r0 * 64 + chs * 8];

    // advancing global pointers (K: +64 rows/tile; V: +64 cols/tile)
    const __bf16* kp0 = Kb + (size_t)b * SK * DD + h * HS + (size_t)r0 * DD + c8 * 8;
    const __bf16* vp0 = Vt + (size_t)bh * HS * SK + (size_t)r0 * SK + c8 * 8;

    // per-lane swizzled LDS read offsets (elements): row term lm*64 folded in
    int o0 = lm * 64 + ((lk ^ (lm & 7)) * 8);
    int o1 = lm * 64 + (((4 + lk) ^ (lm & 7)) * 8);

    float4 kr0, vr0;   // NAMED regs only (arrays -> scratch)
#define FA_LOAD()                                                                \
    kr0 = *(const float4*)kp0; vr0 = *(const float4*)vp0;                        \
    kp0 += (size_t)64 * DD; vp0 += 64;
#define FA_WRITE(BUF)                                                            \
    *(float4*)(ksl0 + (BUF) * 4096) = kr0;                                       \
    *(float4*)(vsl0 + (BUF) * 4096) = vr0;

    FA_LOAD();
    FA_WRITE(0);
    __syncthreads();

    bf16x8 ones;
#pragma unroll
    for (int j = 0; j < 8; ++j) ones[j] = (__bf16)1.0f;

    f32x4 o[4] = {};
    f32x4 o_s = {};

    for (int it = 0; it < 32; ++it) {
        int buf = it & 1;
        if (it + 1 < 32) { FA_LOAD(); }   // issue early; hides under compute

        const __bf16* KsB = &Ks[buf][0];
        const __bf16* VsB = &Vs[buf][0];

        // S^T = K Q^T : st[n], lane holds P[q=w*16+lm][kv=16n+4lk+r]
        f32x4 st[4] = {};
        __builtin_amdgcn_s_setprio(1);
#pragma unroll
        for (int kk = 0; kk < 2; ++kk) {
#pragma unroll
            for (int n = 0; n < 4; ++n) {
                bf16x8 kf = *(const bf16x8*)&KsB[(kk ? o1 : o0) + n * 1024];
                st[n] = __builtin_amdgcn_mfma_f32_16x16x32_bf16(kf, qf[kk], st[n], 0, 0, 0);
            }
        }
        __builtin_amdgcn_s_setprio(0);

        // P = exp2(S) fused into fragment assembly; PV + ones-column row-sum
#pragma unroll
        for (int kk = 0; kk < 2; ++kk) {
            bf16x8 pa;
#pragma unroll
            for (int j = 0; j < 8; ++j)
                pa[j] = (__bf16)FEXP2(st[2 * kk + (j >> 2)][j & 3]);
            __builtin_amdgcn_s_setprio(1);
            o_s = __builtin_amdgcn_mfma_f32_16x16x32_bf16(pa, ones, o_s, 0, 0, 0);
#pragma unroll
            for (int dn = 0; dn < 4; ++dn) {
                bf16x8 vf = *(const bf16x8*)&VsB[(kk ? o1 : o0) + dn * 1024];
                o[dn] = __builtin_amdgcn_mfma_f32_16x16x32_bf16(pa, vf, o[dn], 0, 0, 0);
            }
            __builtin_amdgcn_s_setprio(0);
        }

        if (it + 1 < 32) { FA_WRITE(buf ^ 1); }        // lands in the other buffer
        __syncthreads();                               // one barrier per tile
    }

    // epilogue: o_s[r] holds rowsum(q = w*16 + lk*4 + r) at every lm lane
    f32x4 inv;
#pragma unroll
    for (int r = 0; r < 4; ++r) inv[r] = 1.f / o_s[r];
#pragma unroll
    for (int dn = 0; dn < 4; ++dn)
#pragma unroll
        for (int r = 0; r < 4; ++r) {
            int row = q0 + w * 16 + lk * 4 + r;
            int col = h * HS + dn * 16 + lm;
            O[(size_t)(b * SQ + row) * DD + col] = (__bf16)(o[dn][r] * inv[r]);
        }
}

extern "C" void kernel_launch(void* const* d_in, const int* in_sizes, int n_in,
                              void* d_out, int out_size, void* d_ws, size_t ws_size,
                              hipStream_t stream) {
    const float* inputs  = (const float*)d_in[0];
    const float* context = (const float*)d_in[1];
    const float* Wq = (const float*)d_in[2];
    const float* bq = (const float*)d_in[3];
    const float* Wk = (const float*)d_in[4];
    const float* bk = (const float*)d_in[5];
    const float* Wv = (const float*)d_in[6];
    const float* bv = (const float*)d_in[7];
    const float* Wo = (const float*)d_in[8];
    const float* bo = (const float*)d_in[9];
    float* out = (float*)d_out;

    char* ws = (char*)d_ws;
    const size_t SEG = (size_t)4096 * 1024 * sizeof(__bf16);  // 8 MB
    __bf16* attb = (__bf16*)(ws + 0 * SEG);   // attention output (bf16)
    __bf16* Wt   = (__bf16*)(ws + 2 * SEG);   // 4 x 1024x1024 bf16 (B-swizzled layout)
    __bf16* Qb   = (__bf16*)(ws + 3 * SEG);
    __bf16* Kbuf = (__bf16*)(ws + 4 * SEG);
    __bf16* Vtb  = (__bf16*)(ws + 5 * SEG);   // V transposed + sigma-permuted by gemm_qkv

    wtrans<<<dim3(32, 32, 4), dim3(32, 8), 0, stream>>>(Wq, Wk, Wv, Wo, Wt);

    gemm_qkv<<<dim3(16, 96), 256, 0, stream>>>(inputs, context, Wt, bq, bk, bv,
                                               Qb, Kbuf, Vtb, SCALE * LOG2E);

    flash_attn<<<dim3(16, 32), 512, 0, stream>>>(Qb, Kbuf, Vtb, attb);

    gemm_out64<<<dim3(8, 64), 256, 0, stream>>>(attb, Wt + (size_t)3 * DD * DD, bo, out);
}